// Round 6
// baseline (211.312 us; speedup 1.0000x reference)
//
#include <hip/hip_runtime.h>
#include <hip/hip_bf16.h>

#define T_TOT 2304
#define DDIM  1024
#define NH    16
#define DK    64
#define SLEN  128
#define SEQ   2048

typedef __bf16 bf16x8 __attribute__((ext_vector_type(8)));
typedef __bf16 bf16x4 __attribute__((ext_vector_type(4)));
typedef float  f32x4  __attribute__((ext_vector_type(4)));

__device__ __forceinline__ void async_copy16(const void* gsrc, void* ldst) {
  __builtin_amdgcn_global_load_lds(
      (const __attribute__((address_space(1))) void*)gsrc,
      (__attribute__((address_space(3))) void*)ldst, 16, 0, 0);
}

// ---------------- convert: x -> bf16 (vectorized); W[h][d][n] -> Wt[m][h][n][d] via LDS transpose
__global__ __launch_bounds__(256) void convert_kernel(
    const float* __restrict__ x,
    const float* __restrict__ Wq, const float* __restrict__ Wk,
    const float* __restrict__ Wv, const float* __restrict__ Wqs,
    const float* __restrict__ Wks, const float* __restrict__ Wvs,
    __bf16* __restrict__ xb, __bf16* __restrict__ Wt) {
  const int b = blockIdx.x;
  const int tid = threadIdx.x;
  if (b < 576) {
    const float4* xin = (const float4*)x;
#pragma unroll
    for (int it = 0; it < 4; ++it) {
      int idx4 = b * 1024 + it * 256 + tid;
      float4 v = xin[idx4];
      bf16x4 o;
      o[0] = (__bf16)v.x; o[1] = (__bf16)v.y; o[2] = (__bf16)v.z; o[3] = (__bf16)v.w;
      *(bf16x4*)(xb + (size_t)idx4 * 4) = o;
    }
    return;
  }
  __shared__ float tile[64 * 65];
  const int wb = b - 576;
  const int m  = wb >> 8;
  const int rem = wb & 255;
  const int h  = rem >> 4;
  const int dt = rem & 15;
  const int d0 = dt * 64;
  const float* Wsrc = (m == 0 ? Wq : m == 1 ? Wk : m == 2 ? Wv
                      : m == 3 ? Wqs : m == 4 ? Wks : Wvs) + (size_t)h * (DDIM * DK);
#pragma unroll
  for (int rr = 0; rr < 4; ++rr) {
    int drow = rr * 16 + (tid >> 4);
    int nc   = (tid & 15) * 4;
    float4 v = *(const float4*)(Wsrc + (size_t)(d0 + drow) * DK + nc);
    tile[(nc + 0) * 65 + drow] = v.x;
    tile[(nc + 1) * 65 + drow] = v.y;
    tile[(nc + 2) * 65 + drow] = v.z;
    tile[(nc + 3) * 65 + drow] = v.w;
  }
  __syncthreads();
  {
    int n  = tid >> 2;
    int rg = (tid & 3) * 16;
    __bf16* dst = Wt + (((size_t)(m * NH + h)) * DK + n) * DDIM + d0 + rg;
    bf16x8 o0, o1;
#pragma unroll
    for (int e = 0; e < 8; e++) o0[e] = (__bf16)tile[n * 65 + rg + e];
#pragma unroll
    for (int e = 0; e < 8; e++) o1[e] = (__bf16)tile[n * 65 + rg + 8 + e];
    *(bf16x8*)dst = o0;
    *(bf16x8*)(dst + 8) = o1;
  }
}

// ---------------- projection + l2norm, BK=128; waves_per_eu(2,2): schedule for ILP
__global__ __launch_bounds__(256)
__attribute__((amdgpu_waves_per_eu(2, 2)))
void proj_kernel(
    const __bf16* __restrict__ xb, const __bf16* __restrict__ Wt,
    const float* __restrict__ scal,
    __bf16* __restrict__ qkv, __bf16* __restrict__ vt) {
  const int which = blockIdx.x;
  const int rt    = blockIdx.y;
  const int h     = blockIdx.z;
  const int r0    = rt * 128;
  const int m     = (rt == 0 || rt == 17) ? which + 3 : which;

  __shared__ __bf16 Xs[128 * 128];   // 32 KB
  __shared__ __bf16 Wsh[64 * 128];   // 16 KB

  const int tid  = threadIdx.x;
  const int wave = tid >> 6, lane = tid & 63;
  const int quad = lane >> 4, lc = lane & 15;

  const __bf16* Wbase = Wt + ((size_t)(m * NH + h)) * (DK * DDIM);

  const f32x4 fz = {0.f, 0.f, 0.f, 0.f};
  f32x4 acc[2][4];
#pragma unroll
  for (int i = 0; i < 2; i++)
#pragma unroll
    for (int j = 0; j < 4; j++) acc[i][j] = fz;

  for (int k0 = 0; k0 < DDIM; k0 += 128) {
#pragma unroll
    for (int it = 0; it < 8; ++it) {
      int L = it * 256 + tid;
      int row = L >> 4, c = (L & 15) ^ ((L >> 4) & 15);
      async_copy16(xb + (size_t)(r0 + row) * DDIM + k0 + c * 8,
                   (char*)Xs + (size_t)(it * 256 + wave * 64) * 16);
    }
#pragma unroll
    for (int it = 0; it < 4; ++it) {
      int L = it * 256 + tid;
      int row = L >> 4, c = (L & 15) ^ ((L >> 4) & 15);
      async_copy16(Wbase + (size_t)row * DDIM + k0 + c * 8,
                   (char*)Wsh + (size_t)(it * 256 + wave * 64) * 16);
    }
    __syncthreads();
#pragma unroll
    for (int kk = 0; kk < 4; kk++) {
      bf16x8 afr[2], bfr[4];
#pragma unroll
      for (int i = 0; i < 2; i++) {
        int row = wave * 32 + i * 16 + lc;
        int ch  = (kk * 4 + quad) ^ (row & 15);
        afr[i] = *(const bf16x8*)(Xs + (row * 16 + ch) * 8);
      }
#pragma unroll
      for (int j = 0; j < 4; j++) {
        int row = j * 16 + lc;
        int ch  = (kk * 4 + quad) ^ (row & 15);
        bfr[j] = *(const bf16x8*)(Wsh + (row * 16 + ch) * 8);
      }
#pragma unroll
      for (int i = 0; i < 2; i++)
#pragma unroll
        for (int j = 0; j < 4; j++)
          acc[i][j] = __builtin_amdgcn_mfma_f32_16x16x32_bf16(afr[i], bfr[j], acc[i][j], 0, 0, 0);
    }
    __syncthreads();
  }

  float inv4[2][4];
  const float qscale = (which == 0) ? scal[h] : 1.0f;
#pragma unroll
  for (int i = 0; i < 2; i++) {
#pragma unroll
    for (int r = 0; r < 4; r++) {
      float s = 0.f;
#pragma unroll
      for (int j = 0; j < 4; j++) { float v = acc[i][j][r]; s += v * v; }
#pragma unroll
      for (int off = 1; off < 16; off <<= 1) s += __shfl_xor(s, off, 64);
      inv4[i][r] = qscale / fmaxf(sqrtf(s), 1e-12f);
    }
  }
  if (which == 2) {
    __bf16* vtp = vt + (size_t)h * (DK * T_TOT);
#pragma unroll
    for (int i = 0; i < 2; i++) {
      int rowbase = r0 + wave * 32 + i * 16 + quad * 4;
#pragma unroll
      for (int j = 0; j < 4; j++) {
        bf16x4 o;
#pragma unroll
        for (int r = 0; r < 4; r++) o[r] = (__bf16)(acc[i][j][r] * inv4[i][r]);
        *(bf16x4*)(vtp + (size_t)(j * 16 + lc) * T_TOT + rowbase) = o;
      }
    }
  } else {
    __bf16* outp = qkv + ((size_t)(which * NH + h)) * ((size_t)T_TOT * DK);
#pragma unroll
    for (int i = 0; i < 2; i++)
#pragma unroll
      for (int r = 0; r < 4; r++) {
        int row = r0 + wave * 32 + i * 16 + quad * 4 + r;
#pragma unroll
        for (int j = 0; j < 4; j++)
          outp[(size_t)row * DK + j * 16 + lc] = (__bf16)(acc[i][j][r] * inv4[i][r]);
      }
  }
}

// ---------------- flash attention v6: BN=64, 4-way kv split, loop-carried K/V
// register prefetch (scheduler cannot sink loads across the back-edge),
// waves_per_eu(2,2) -> 256-VGPR budget, ILP-oriented scheduling.
__global__ __launch_bounds__(256)
__attribute__((amdgpu_waves_per_eu(2, 2)))
void attn_kernel(
    const __bf16* __restrict__ qkv, const __bf16* __restrict__ vt,
    float* __restrict__ out) {
  const int b    = blockIdx.x;          // 0..2303
  const int h    = b & 15;
  const int qt   = 143 - (b >> 4);      // big work first
  const int q0w  = qt * 16;
  const int tid  = threadIdx.x;
  const int wave = tid >> 6, lane = tid & 63;
  const int quad = lane >> 4, lc = lane & 15;

  const __bf16* qp = qkv + ((size_t)h) * ((size_t)T_TOT * DK);
  const __bf16* kp = qkv + ((size_t)(NH + h)) * ((size_t)T_TOT * DK);
  const __bf16* vp = vt + (size_t)h * (DK * T_TOT);

  __shared__ __bf16 Ps[4][16 * 64];     // per-wave P tile [q][kv], swizzled chunks
  __shared__ float  OL[3][1024];        // waves 1..3 O^T for merge
  __shared__ float  mlL[3][2][16];

  // Q B-frag (persistent)
  bf16x8 qf[2];
#pragma unroll
  for (int kk = 0; kk < 2; kk++)
    qf[kk] = *(const bf16x8*)(qp + (size_t)(q0w + lc) * DK + kk * 32 + quad * 8);

  const f32x4 fz = {0.f, 0.f, 0.f, 0.f};
  f32x4 acc_o[4];                       // O^T: d = ct*16+quad*4+r, q = lc
#pragma unroll
  for (int ct = 0; ct < 4; ct++) acc_o[ct] = fz;
  float m_i = -__builtin_inff(), l_i = 0.f;

  // 64-wide kv tiles, contiguous 4-way split among waves
  const int ustart = (q0w >= SLEN + SEQ) ? 2 : 0;
  const int uend   = q0w >> 6;
  const int nu     = uend - ustart + 1;
  const int b0     = ustart + ((nu * wave) >> 2);
  const int b1     = ustart + ((nu * (wave + 1)) >> 2);

  bf16x8 kA[4][2], vA[2][4];
  if (b0 < b1) {
    const int c0 = b0 * 64;
#pragma unroll
    for (int ct = 0; ct < 4; ct++)
#pragma unroll
      for (int kk = 0; kk < 2; kk++)
        kA[ct][kk] = *(const bf16x8*)(kp + (size_t)(c0 + ct * 16 + lc) * DK + kk * 32 + quad * 8);
#pragma unroll
    for (int kq = 0; kq < 2; kq++)
#pragma unroll
      for (int ct = 0; ct < 4; ct++)
        vA[kq][ct] = *(const bf16x8*)(vp + (size_t)(ct * 16 + lc) * T_TOT + c0 + kq * 32 + quad * 8);
  }

  for (int u = b0; u < b1; ++u) {
    const int c0 = u * 64;
    const bool diag = (u == uend);
    // ---- prefetch next tile (clamped; last iter re-reads same tile from L1)
    const int c0n = (u + 1 < b1 ? u + 1 : u) * 64;
    bf16x8 kN[4][2], vN[2][4];
#pragma unroll
    for (int ct = 0; ct < 4; ct++)
#pragma unroll
      for (int kk = 0; kk < 2; kk++)
        kN[ct][kk] = *(const bf16x8*)(kp + (size_t)(c0n + ct * 16 + lc) * DK + kk * 32 + quad * 8);
#pragma unroll
    for (int kq = 0; kq < 2; kq++)
#pragma unroll
      for (int ct = 0; ct < 4; ct++)
        vN[kq][ct] = *(const bf16x8*)(vp + (size_t)(ct * 16 + lc) * T_TOT + c0n + kq * 32 + quad * 8);

    // S^T = K Q^T : C[kv=ct*16+quad*4+r][q=lc]
    f32x4 s[4];
#pragma unroll
    for (int ct = 0; ct < 4; ct++) {
      s[ct] = fz;
#pragma unroll
      for (int kk = 0; kk < 2; kk++)
        s[ct] = __builtin_amdgcn_mfma_f32_16x16x32_bf16(kA[ct][kk], qf[kk], s[ct], 0, 0, 0);
    }

    // softmax over 64 kv (in-place), 2 cross-quad shuffles per reduce
    float mx = -__builtin_inff();
#pragma unroll
    for (int ct = 0; ct < 4; ct++)
#pragma unroll
      for (int r = 0; r < 4; r++) {
        float v = s[ct][r];
        if (diag && (c0 + ct * 16 + quad * 4 + r) > (q0w + lc)) v = -__builtin_inff();
        s[ct][r] = v;
        mx = fmaxf(mx, v);
      }
    mx = fmaxf(mx, __shfl_xor(mx, 16, 64));
    mx = fmaxf(mx, __shfl_xor(mx, 32, 64));
    float mnew  = fmaxf(m_i, mx);
    float alpha = __expf(m_i - mnew);
    float rs = 0.f;
#pragma unroll
    for (int ct = 0; ct < 4; ct++)
#pragma unroll
      for (int r = 0; r < 4; r++) {
        float pe = __expf(s[ct][r] - mnew);
        s[ct][r] = pe;
        rs += pe;
      }
    rs += __shfl_xor(rs, 16, 64);
    rs += __shfl_xor(rs, 32, 64);
    l_i = l_i * alpha + rs;
    m_i = mnew;
#pragma unroll
    for (int ct = 0; ct < 4; ct++)
#pragma unroll
      for (int r = 0; r < 4; r++) acc_o[ct][r] *= alpha;

    // write P to wave-local LDS: [q=lc][kv], chunk swizzle cc' = cc ^ (lc&7)
#pragma unroll
    for (int ct = 0; ct < 4; ct++) {
      bf16x4 pb;
#pragma unroll
      for (int r = 0; r < 4; r++) pb[r] = (__bf16)s[ct][r];
      int cc = ct * 2 + (quad >> 1);
      int el = lc * 64 + ((cc ^ (lc & 7)) * 8) + (quad & 1) * 4;
      *(bf16x4*)(&Ps[wave][el]) = pb;
    }

    // O^T += V^T P^T (masked cols have P=0 -> unconditional correct)
#pragma unroll
    for (int kq = 0; kq < 2; kq++) {
      int cc = kq * 4 + quad;
      bf16x8 pB = *(const bf16x8*)(&Ps[wave][lc * 64 + ((cc ^ (lc & 7)) * 8)]);
#pragma unroll
      for (int ct = 0; ct < 4; ct++)
        acc_o[ct] = __builtin_amdgcn_mfma_f32_16x16x32_bf16(vA[kq][ct], pB, acc_o[ct], 0, 0, 0);
    }

    // rotate prefetch buffers
#pragma unroll
    for (int ct = 0; ct < 4; ct++)
#pragma unroll
      for (int kk = 0; kk < 2; kk++) kA[ct][kk] = kN[ct][kk];
#pragma unroll
    for (int kq = 0; kq < 2; kq++)
#pragma unroll
      for (int ct = 0; ct < 4; ct++) vA[kq][ct] = vN[kq][ct];
  }

  // merge 4 partial results (log-sum-exp combine)
  if (wave != 0) {
#pragma unroll
    for (int ct = 0; ct < 4; ct++)
      *(f32x4*)(&OL[wave - 1][((ct * 4 + quad) * 16 + lc) * 4]) = acc_o[ct];
    if (quad == 0) { mlL[wave - 1][0][lc] = m_i; mlL[wave - 1][1][lc] = l_i; }
  }
  __syncthreads();
  if (wave == 0) {
    float mw[3], lw[3];
#pragma unroll
    for (int w = 0; w < 3; w++) { mw[w] = mlL[w][0][lc]; lw[w] = mlL[w][1][lc]; }
    float M = m_i;
#pragma unroll
    for (int w = 0; w < 3; w++) M = fmaxf(M, mw[w]);
    float a0 = __expf(m_i - M);
    float aw[3];
    float Lt = a0 * l_i;
#pragma unroll
    for (int w = 0; w < 3; w++) { aw[w] = __expf(mw[w] - M); Lt += aw[w] * lw[w]; }
    float invl = 1.0f / Lt;
#pragma unroll
    for (int ct = 0; ct < 4; ct++) {
      f32x4 o;
#pragma unroll
      for (int r = 0; r < 4; r++) o[r] = a0 * acc_o[ct][r];
#pragma unroll
      for (int w = 0; w < 3; w++) {
        f32x4 ow = *(const f32x4*)(&OL[w][((ct * 4 + quad) * 16 + lc) * 4]);
#pragma unroll
        for (int r = 0; r < 4; r++) o[r] += aw[w] * ow[r];
      }
#pragma unroll
      for (int r = 0; r < 4; r++) o[r] *= invl;
      *(f32x4*)(&out[((size_t)h * T_TOT + q0w + lc) * DK + ct * 16 + quad * 4]) = o;
    }
  }
}

extern "C" void kernel_launch(void* const* d_in, const int* in_sizes, int n_in,
                              void* d_out, int out_size, void* d_ws, size_t ws_size,
                              hipStream_t stream) {
  const float* x    = (const float*)d_in[0];
  const float* Wq   = (const float*)d_in[1];
  const float* Wk   = (const float*)d_in[2];
  const float* Wv   = (const float*)d_in[3];
  const float* Wqs  = (const float*)d_in[4];
  const float* Wks  = (const float*)d_in[5];
  const float* Wvs  = (const float*)d_in[6];
  const float* scal = (const float*)d_in[7];
  float* out = (float*)d_out;

  char* ws = (char*)d_ws;
  size_t off = 0;
  __bf16* xb  = (__bf16*)(ws + off); off += (size_t)T_TOT * DDIM * 2;
  __bf16* Wt  = (__bf16*)(ws + off); off += (size_t)6 * NH * DK * DDIM * 2;
  __bf16* qkv = (__bf16*)(ws + off); off += (size_t)2 * NH * T_TOT * DK * 2;
  __bf16* vt  = (__bf16*)(ws + off);

  convert_kernel<<<2112, 256, 0, stream>>>(x, Wq, Wk, Wv, Wqs, Wks, Wvs, xb, Wt);
  proj_kernel<<<dim3(3, 18, NH), 256, 0, stream>>>(xb, Wt, scal, qkv, vt);
  attn_kernel<<<dim3(2304), 256, 0, stream>>>(qkv, vt, out);
}

// Round 7
// 167.599 us; speedup vs baseline: 1.2608x; 1.2608x over previous
//
#include <hip/hip_runtime.h>
#include <hip/hip_bf16.h>

#define T_TOT 2304
#define DDIM  1024
#define NH    16
#define DK    64
#define SLEN  128
#define SEQ   2048

typedef __bf16 bf16x8 __attribute__((ext_vector_type(8)));
typedef __bf16 bf16x4 __attribute__((ext_vector_type(4)));
typedef float  f32x4  __attribute__((ext_vector_type(4)));

__device__ __forceinline__ void async_copy16(const void* gsrc, void* ldst) {
  __builtin_amdgcn_global_load_lds(
      (const __attribute__((address_space(1))) void*)gsrc,
      (__attribute__((address_space(3))) void*)ldst, 16, 0, 0);
}

// ---------------- convert: x -> bf16 (vectorized); W[h][d][n] -> Wt[m][h][n][d] via LDS transpose
__global__ __launch_bounds__(256) void convert_kernel(
    const float* __restrict__ x,
    const float* __restrict__ Wq, const float* __restrict__ Wk,
    const float* __restrict__ Wv, const float* __restrict__ Wqs,
    const float* __restrict__ Wks, const float* __restrict__ Wvs,
    __bf16* __restrict__ xb, __bf16* __restrict__ Wt) {
  const int b = blockIdx.x;
  const int tid = threadIdx.x;
  if (b < 576) {
    const float4* xin = (const float4*)x;
#pragma unroll
    for (int it = 0; it < 4; ++it) {
      int idx4 = b * 1024 + it * 256 + tid;
      float4 v = xin[idx4];
      bf16x4 o;
      o[0] = (__bf16)v.x; o[1] = (__bf16)v.y; o[2] = (__bf16)v.z; o[3] = (__bf16)v.w;
      *(bf16x4*)(xb + (size_t)idx4 * 4) = o;
    }
    return;
  }
  __shared__ float tile[64 * 65];
  const int wb = b - 576;
  const int m  = wb >> 8;
  const int rem = wb & 255;
  const int h  = rem >> 4;
  const int dt = rem & 15;
  const int d0 = dt * 64;
  const float* Wsrc = (m == 0 ? Wq : m == 1 ? Wk : m == 2 ? Wv
                      : m == 3 ? Wqs : m == 4 ? Wks : Wvs) + (size_t)h * (DDIM * DK);
#pragma unroll
  for (int rr = 0; rr < 4; ++rr) {
    int drow = rr * 16 + (tid >> 4);
    int nc   = (tid & 15) * 4;
    float4 v = *(const float4*)(Wsrc + (size_t)(d0 + drow) * DK + nc);
    tile[(nc + 0) * 65 + drow] = v.x;
    tile[(nc + 1) * 65 + drow] = v.y;
    tile[(nc + 2) * 65 + drow] = v.z;
    tile[(nc + 3) * 65 + drow] = v.w;
  }
  __syncthreads();
  {
    int n  = tid >> 2;
    int rg = (tid & 3) * 16;
    __bf16* dst = Wt + (((size_t)(m * NH + h)) * DK + n) * DDIM + d0 + rg;
    bf16x8 o0, o1;
#pragma unroll
    for (int e = 0; e < 8; e++) o0[e] = (__bf16)tile[n * 65 + rg + e];
#pragma unroll
    for (int e = 0; e < 8; e++) o1[e] = (__bf16)tile[n * 65 + rg + 8 + e];
    *(bf16x8*)dst = o0;
    *(bf16x8*)(dst + 8) = o1;
  }
}

// ---------------- projection + l2norm, BK=128
__global__ __launch_bounds__(256)
__attribute__((amdgpu_waves_per_eu(2, 2)))
void proj_kernel(
    const __bf16* __restrict__ xb, const __bf16* __restrict__ Wt,
    const float* __restrict__ scal,
    __bf16* __restrict__ qkv, __bf16* __restrict__ vt) {
  const int which = blockIdx.x;
  const int rt    = blockIdx.y;
  const int h     = blockIdx.z;
  const int r0    = rt * 128;
  const int m     = (rt == 0 || rt == 17) ? which + 3 : which;

  __shared__ __bf16 Xs[128 * 128];   // 32 KB
  __shared__ __bf16 Wsh[64 * 128];   // 16 KB

  const int tid  = threadIdx.x;
  const int wave = tid >> 6, lane = tid & 63;
  const int quad = lane >> 4, lc = lane & 15;

  const __bf16* Wbase = Wt + ((size_t)(m * NH + h)) * (DK * DDIM);

  const f32x4 fz = {0.f, 0.f, 0.f, 0.f};
  f32x4 acc[2][4];
#pragma unroll
  for (int i = 0; i < 2; i++)
#pragma unroll
    for (int j = 0; j < 4; j++) acc[i][j] = fz;

  for (int k0 = 0; k0 < DDIM; k0 += 128) {
#pragma unroll
    for (int it = 0; it < 8; ++it) {
      int L = it * 256 + tid;
      int row = L >> 4, c = (L & 15) ^ ((L >> 4) & 15);
      async_copy16(xb + (size_t)(r0 + row) * DDIM + k0 + c * 8,
                   (char*)Xs + (size_t)(it * 256 + wave * 64) * 16);
    }
#pragma unroll
    for (int it = 0; it < 4; ++it) {
      int L = it * 256 + tid;
      int row = L >> 4, c = (L & 15) ^ ((L >> 4) & 15);
      async_copy16(Wbase + (size_t)row * DDIM + k0 + c * 8,
                   (char*)Wsh + (size_t)(it * 256 + wave * 64) * 16);
    }
    __syncthreads();
#pragma unroll
    for (int kk = 0; kk < 4; kk++) {
      bf16x8 afr[2], bfr[4];
#pragma unroll
      for (int i = 0; i < 2; i++) {
        int row = wave * 32 + i * 16 + lc;
        int ch  = (kk * 4 + quad) ^ (row & 15);
        afr[i] = *(const bf16x8*)(Xs + (row * 16 + ch) * 8);
      }
#pragma unroll
      for (int j = 0; j < 4; j++) {
        int row = j * 16 + lc;
        int ch  = (kk * 4 + quad) ^ (row & 15);
        bfr[j] = *(const bf16x8*)(Wsh + (row * 16 + ch) * 8);
      }
#pragma unroll
      for (int i = 0; i < 2; i++)
#pragma unroll
        for (int j = 0; j < 4; j++)
          acc[i][j] = __builtin_amdgcn_mfma_f32_16x16x32_bf16(afr[i], bfr[j], acc[i][j], 0, 0, 0);
    }
    __syncthreads();
  }

  float inv4[2][4];
  const float qscale = (which == 0) ? scal[h] : 1.0f;
#pragma unroll
  for (int i = 0; i < 2; i++) {
#pragma unroll
    for (int r = 0; r < 4; r++) {
      float s = 0.f;
#pragma unroll
      for (int j = 0; j < 4; j++) { float v = acc[i][j][r]; s += v * v; }
#pragma unroll
      for (int off = 1; off < 16; off <<= 1) s += __shfl_xor(s, off, 64);
      inv4[i][r] = qscale / fmaxf(sqrtf(s), 1e-12f);
    }
  }
  if (which == 2) {
    __bf16* vtp = vt + (size_t)h * (DK * T_TOT);
#pragma unroll
    for (int i = 0; i < 2; i++) {
      int rowbase = r0 + wave * 32 + i * 16 + quad * 4;
#pragma unroll
      for (int j = 0; j < 4; j++) {
        bf16x4 o;
#pragma unroll
        for (int r = 0; r < 4; r++) o[r] = (__bf16)(acc[i][j][r] * inv4[i][r]);
        *(bf16x4*)(vtp + (size_t)(j * 16 + lc) * T_TOT + rowbase) = o;
      }
    }
  } else {
    __bf16* outp = qkv + ((size_t)(which * NH + h)) * ((size_t)T_TOT * DK);
#pragma unroll
    for (int i = 0; i < 2; i++)
#pragma unroll
      for (int r = 0; r < 4; r++) {
        int row = r0 + wave * 32 + i * 16 + quad * 4 + r;
#pragma unroll
        for (int j = 0; j < 4; j++)
          outp[(size_t)row * DK + j * 16 + lc] = (__bf16)(acc[i][j][r] * inv4[i][r]);
      }
  }
}

// ---------------- flash attention v7: block-cooperative double-buffered LDS staging
// Block = 256 thr = 4 waves; BM=64 (16 q-rows/wave), BN=64; K/V via global_load_lds;
// 1 barrier per kv tile (next-tile loads issued right after barrier, drain overlaps compute).
__global__ __launch_bounds__(256) void attn_kernel(
    const __bf16* __restrict__ qkv, const __bf16* __restrict__ vt,
    float* __restrict__ out) {
  const int b    = blockIdx.x;          // 0..575
  const int h    = b & 15;
  const int qg   = 35 - (b >> 4);       // 64-row q block, big work first
  const int q0b  = qg * 64;
  const int tid  = threadIdx.x;
  const int wave = tid >> 6, lane = tid & 63;
  const int quad = lane >> 4, lc = lane & 15;
  const int q0w  = q0b + wave * 16;

  const __bf16* qp = qkv + ((size_t)h) * ((size_t)T_TOT * DK);
  const __bf16* kp = qkv + ((size_t)(NH + h)) * ((size_t)T_TOT * DK);
  const __bf16* vp = vt + (size_t)h * (DK * T_TOT);

  __shared__ __bf16 Ks[2][64 * 64];     // [kv][d], swizzled 16B chunks (8/row)
  __shared__ __bf16 Vs[2][64 * 64];     // [d][kv], swizzled
  __shared__ __bf16 Ps[4][16 * 64];     // per-wave P tile

  // Q B-frag (persistent): Q[q=lc][d]
  bf16x8 qf[2];
#pragma unroll
  for (int kk = 0; kk < 2; kk++)
    qf[kk] = *(const bf16x8*)(qp + (size_t)(q0w + lc) * DK + kk * 32 + quad * 8);

  const f32x4 fz = {0.f, 0.f, 0.f, 0.f};
  f32x4 acc_o[4];                       // O^T: d = ct*16+quad*4+r, q = lc
#pragma unroll
  for (int ct = 0; ct < 4; ct++) acc_o[ct] = fz;
  float m_i = -__builtin_inff(), l_i = 0.f;

  const int jstart = (q0b >= SLEN + SEQ) ? 2 : 0;
  const int jend   = qg;                // (q0b+63)>>6 == qg

  // stage tile j into buffer bufi: K 512 chunks + V 512 chunks, 4 per thread
  auto stage = [&](int j, int bufi) {
    const __bf16* kT = kp + (size_t)j * 64 * DK;
#pragma unroll
    for (int it = 0; it < 2; ++it) {
      int L = it * 256 + tid;
      int row = L >> 3, c = (L & 7) ^ (L >> 3 & 7);
      async_copy16(kT + row * DK + c * 8,
                   (char*)&Ks[bufi][0] + (size_t)(it * 256 + wave * 64) * 16);
    }
#pragma unroll
    for (int it = 0; it < 2; ++it) {
      int L = it * 256 + tid;
      int row = L >> 3, c = (L & 7) ^ (L >> 3 & 7);
      async_copy16(vp + (size_t)row * T_TOT + j * 64 + c * 8,
                   (char*)&Vs[bufi][0] + (size_t)(it * 256 + wave * 64) * 16);
    }
  };

  stage(jstart, 0);
  int cur = 0;

  for (int j = jstart; j <= jend; ++j) {
    __syncthreads();                    // drains loads of buf cur (vmcnt0) + joins waves
    if (j < jend) stage(j + 1, cur ^ 1);

    const int c0 = j * 64;
    const bool diag = (j == jend);

    // S^T = K Q^T : C[kv=ct*16+quad*4+r][q=lc], A = K rows from LDS
    f32x4 s[4];
#pragma unroll
    for (int ct = 0; ct < 4; ct++) {
      s[ct] = fz;
#pragma unroll
      for (int kk = 0; kk < 2; kk++) {
        int row = ct * 16 + lc;
        bf16x8 kA = *(const bf16x8*)(&Ks[cur][(row * 8 + (((kk * 4 + quad)) ^ (row & 7))) * 8]);
        s[ct] = __builtin_amdgcn_mfma_f32_16x16x32_bf16(kA, qf[kk], s[ct], 0, 0, 0);
      }
    }

    // softmax over 64 kv (in-place), 2 cross-quad shuffles per reduce
    float mx = -__builtin_inff();
#pragma unroll
    for (int ct = 0; ct < 4; ct++)
#pragma unroll
      for (int r = 0; r < 4; r++) {
        float v = s[ct][r];
        if (diag && (c0 + ct * 16 + quad * 4 + r) > (q0w + lc)) v = -__builtin_inff();
        s[ct][r] = v;
        mx = fmaxf(mx, v);
      }
    mx = fmaxf(mx, __shfl_xor(mx, 16, 64));
    mx = fmaxf(mx, __shfl_xor(mx, 32, 64));
    float mnew  = fmaxf(m_i, mx);
    float alpha = __expf(m_i - mnew);
    float rs = 0.f;
#pragma unroll
    for (int ct = 0; ct < 4; ct++)
#pragma unroll
      for (int r = 0; r < 4; r++) {
        float pe = __expf(s[ct][r] - mnew);
        s[ct][r] = pe;
        rs += pe;
      }
    rs += __shfl_xor(rs, 16, 64);
    rs += __shfl_xor(rs, 32, 64);
    l_i = l_i * alpha + rs;
    m_i = mnew;
#pragma unroll
    for (int ct = 0; ct < 4; ct++)
#pragma unroll
      for (int r = 0; r < 4; r++) acc_o[ct][r] *= alpha;

    // write P to wave-local LDS: [q=lc][kv], chunk swizzle cc' = cc ^ (lc&7)
#pragma unroll
    for (int ct = 0; ct < 4; ct++) {
      bf16x4 pb;
#pragma unroll
      for (int r = 0; r < 4; r++) pb[r] = (__bf16)s[ct][r];
      int cc = ct * 2 + (quad >> 1);
      int el = lc * 64 + ((cc ^ (lc & 7)) * 8) + (quad & 1) * 4;
      *(bf16x4*)(&Ps[wave][el]) = pb;
    }

    // O^T += V^T P^T : A = V^T rows (d) from LDS, B = P (wave-local LDS)
#pragma unroll
    for (int kq = 0; kq < 2; kq++) {
      int cc = kq * 4 + quad;
      bf16x8 pB = *(const bf16x8*)(&Ps[wave][lc * 64 + ((cc ^ (lc & 7)) * 8)]);
#pragma unroll
      for (int ct = 0; ct < 4; ct++) {
        int vrow = ct * 16 + lc;
        bf16x8 vA = *(const bf16x8*)(&Vs[cur][(vrow * 8 + ((cc) ^ (vrow & 7))) * 8]);
        acc_o[ct] = __builtin_amdgcn_mfma_f32_16x16x32_bf16(vA, pB, acc_o[ct], 0, 0, 0);
      }
    }
    cur ^= 1;
  }

  // epilogue: each wave stores its own 16 q-rows (O^T / l)
  float invl = 1.0f / l_i;
#pragma unroll
  for (int ct = 0; ct < 4; ct++) {
    f32x4 o;
#pragma unroll
    for (int r = 0; r < 4; r++) o[r] = acc_o[ct][r] * invl;
    *(f32x4*)(&out[((size_t)h * T_TOT + q0w + lc) * DK + ct * 16 + quad * 4]) = o;
  }
}

extern "C" void kernel_launch(void* const* d_in, const int* in_sizes, int n_in,
                              void* d_out, int out_size, void* d_ws, size_t ws_size,
                              hipStream_t stream) {
  const float* x    = (const float*)d_in[0];
  const float* Wq   = (const float*)d_in[1];
  const float* Wk   = (const float*)d_in[2];
  const float* Wv   = (const float*)d_in[3];
  const float* Wqs  = (const float*)d_in[4];
  const float* Wks  = (const float*)d_in[5];
  const float* Wvs  = (const float*)d_in[6];
  const float* scal = (const float*)d_in[7];
  float* out = (float*)d_out;

  char* ws = (char*)d_ws;
  size_t off = 0;
  __bf16* xb  = (__bf16*)(ws + off); off += (size_t)T_TOT * DDIM * 2;
  __bf16* Wt  = (__bf16*)(ws + off); off += (size_t)6 * NH * DK * DDIM * 2;
  __bf16* qkv = (__bf16*)(ws + off); off += (size_t)2 * NH * T_TOT * DK * 2;
  __bf16* vt  = (__bf16*)(ws + off);

  convert_kernel<<<2112, 256, 0, stream>>>(x, Wq, Wk, Wv, Wqs, Wks, Wvs, xb, Wt);
  proj_kernel<<<dim3(3, 18, NH), 256, 0, stream>>>(xb, Wt, scal, qkv, vt);
  attn_kernel<<<dim3(576), 256, 0, stream>>>(qkv, vt, out);
}

// Round 8
// 163.801 us; speedup vs baseline: 1.2900x; 1.0232x over previous
//
#include <hip/hip_runtime.h>
#include <hip/hip_bf16.h>

#define T_TOT 2304
#define DDIM  1024
#define NH    16
#define DK    64
#define SLEN  128
#define SEQ   2048

typedef __bf16 bf16x8 __attribute__((ext_vector_type(8)));
typedef __bf16 bf16x4 __attribute__((ext_vector_type(4)));
typedef float  f32x4  __attribute__((ext_vector_type(4)));

__device__ __forceinline__ void async_copy16(const void* gsrc, void* ldst) {
  __builtin_amdgcn_global_load_lds(
      (const __attribute__((address_space(1))) void*)gsrc,
      (__attribute__((address_space(3))) void*)ldst, 16, 0, 0);
}

// ---------------- convert: x -> bf16 (vectorized); W[h][d][n] -> Wt[m][h][n][d] via LDS transpose
__global__ __launch_bounds__(256) void convert_kernel(
    const float* __restrict__ x,
    const float* __restrict__ Wq, const float* __restrict__ Wk,
    const float* __restrict__ Wv, const float* __restrict__ Wqs,
    const float* __restrict__ Wks, const float* __restrict__ Wvs,
    __bf16* __restrict__ xb, __bf16* __restrict__ Wt) {
  const int b = blockIdx.x;
  const int tid = threadIdx.x;
  if (b < 576) {
    const float4* xin = (const float4*)x;
#pragma unroll
    for (int it = 0; it < 4; ++it) {
      int idx4 = b * 1024 + it * 256 + tid;
      float4 v = xin[idx4];
      bf16x4 o;
      o[0] = (__bf16)v.x; o[1] = (__bf16)v.y; o[2] = (__bf16)v.z; o[3] = (__bf16)v.w;
      *(bf16x4*)(xb + (size_t)idx4 * 4) = o;
    }
    return;
  }
  __shared__ float tile[64 * 65];
  const int wb = b - 576;
  const int m  = wb >> 8;
  const int rem = wb & 255;
  const int h  = rem >> 4;
  const int dt = rem & 15;
  const int d0 = dt * 64;
  const float* Wsrc = (m == 0 ? Wq : m == 1 ? Wk : m == 2 ? Wv
                      : m == 3 ? Wqs : m == 4 ? Wks : Wvs) + (size_t)h * (DDIM * DK);
#pragma unroll
  for (int rr = 0; rr < 4; ++rr) {
    int drow = rr * 16 + (tid >> 4);
    int nc   = (tid & 15) * 4;
    float4 v = *(const float4*)(Wsrc + (size_t)(d0 + drow) * DK + nc);
    tile[(nc + 0) * 65 + drow] = v.x;
    tile[(nc + 1) * 65 + drow] = v.y;
    tile[(nc + 2) * 65 + drow] = v.z;
    tile[(nc + 3) * 65 + drow] = v.w;
  }
  __syncthreads();
  {
    int n  = tid >> 2;
    int rg = (tid & 3) * 16;
    __bf16* dst = Wt + (((size_t)(m * NH + h)) * DK + n) * DDIM + d0 + rg;
    bf16x8 o0, o1;
#pragma unroll
    for (int e = 0; e < 8; e++) o0[e] = (__bf16)tile[n * 65 + rg + e];
#pragma unroll
    for (int e = 0; e < 8; e++) o1[e] = (__bf16)tile[n * 65 + rg + 8 + e];
    *(bf16x8*)dst = o0;
    *(bf16x8*)(dst + 8) = o1;
  }
}

// ---------------- proj v2: m97-shape GEMM 128x128 tile, N=1024 (all 16 heads fused)
// grid (ntile=8, rt=18, which=3); wave quadrant (wr,wc) 64x64 = one head's cols.
__global__ __launch_bounds__(256) void proj_kernel(
    const __bf16* __restrict__ xb, const __bf16* __restrict__ Wt,
    const float* __restrict__ scal,
    __bf16* __restrict__ qkv, __bf16* __restrict__ vt) {
  const int ntile = blockIdx.x;   // 0..7  (128 N-cols = 2 heads)
  const int rt    = blockIdx.y;   // 0..17 (128 M-rows)
  const int which = blockIdx.z;   // 0=q 1=k 2=v
  const int r0    = rt * 128;
  const int m     = (rt == 0 || rt == 17) ? which + 3 : which;

  __shared__ __bf16 Xs[128 * 64];   // A tile [row][k], swizzled (16 KB)
  __shared__ __bf16 Wsh[128 * 64];  // B tile [n][k], swizzled (16 KB)

  const int tid  = threadIdx.x;
  const int wave = tid >> 6, lane = tid & 63;
  const int quad = lane >> 4, lc = lane & 15;
  const int wr   = wave >> 1, wc = wave & 1;    // wave quadrant
  const int h    = ntile * 2 + wc;              // this wave's head

  // B base: Wt[m][h? no: full N] — Wt[m] is [NH][64][1024] = [N=1024][K]
  const __bf16* Wbase = Wt + ((size_t)m * NH) * (DK * DDIM) + (size_t)(ntile * 128) * DDIM;

  const f32x4 fz = {0.f, 0.f, 0.f, 0.f};
  f32x4 acc[4][4];
#pragma unroll
  for (int i = 0; i < 4; i++)
#pragma unroll
    for (int j = 0; j < 4; j++) acc[i][j] = fz;

  for (int k0 = 0; k0 < DDIM; k0 += 64) {
    // A: 128 rows x 8 chunks = 1024 chunks; swizzle c' = c ^ (row&7)
#pragma unroll
    for (int it = 0; it < 4; ++it) {
      int L = it * 256 + tid;
      int row = L >> 3, c = (L & 7) ^ ((L >> 3) & 7);
      async_copy16(xb + (size_t)(r0 + row) * DDIM + k0 + c * 8,
                   (char*)Xs + (size_t)(it * 256 + wave * 64) * 16);
    }
    // B: 128 n-rows x 8 chunks
#pragma unroll
    for (int it = 0; it < 4; ++it) {
      int L = it * 256 + tid;
      int row = L >> 3, c = (L & 7) ^ ((L >> 3) & 7);
      async_copy16(Wbase + (size_t)row * DDIM + k0 + c * 8,
                   (char*)Wsh + (size_t)(it * 256 + wave * 64) * 16);
    }
    __syncthreads();
#pragma unroll
    for (int kk = 0; kk < 2; kk++) {
      bf16x8 afr[4], bfr[4];
#pragma unroll
      for (int i = 0; i < 4; i++) {
        int row = wr * 64 + i * 16 + lc;
        int ch  = (kk * 4 + quad) ^ (row & 7);
        afr[i] = *(const bf16x8*)(Xs + (row * 8 + ch) * 8);
      }
#pragma unroll
      for (int j = 0; j < 4; j++) {
        int row = wc * 64 + j * 16 + lc;
        int ch  = (kk * 4 + quad) ^ (row & 7);
        bfr[j] = *(const bf16x8*)(Wsh + (row * 8 + ch) * 8);
      }
#pragma unroll
      for (int i = 0; i < 4; i++)
#pragma unroll
        for (int j = 0; j < 4; j++)
          acc[i][j] = __builtin_amdgcn_mfma_f32_16x16x32_bf16(afr[i], bfr[j], acc[i][j], 0, 0, 0);
    }
    __syncthreads();
  }

  // epilogue: fp32 l2norm over this head's 64 cols (j-regs + lc shuffles)
  const float qscale = (which == 0) ? scal[h] : 1.0f;
  float inv4[4][4];
#pragma unroll
  for (int i = 0; i < 4; i++) {
#pragma unroll
    for (int r = 0; r < 4; r++) {
      float s = 0.f;
#pragma unroll
      for (int j = 0; j < 4; j++) { float v = acc[i][j][r]; s += v * v; }
#pragma unroll
      for (int off = 1; off < 16; off <<= 1) s += __shfl_xor(s, off, 64);
      inv4[i][r] = qscale / fmaxf(sqrtf(s), 1e-12f);
    }
  }
  if (which == 2) {
    __bf16* vtp = vt + (size_t)h * (DK * T_TOT);
#pragma unroll
    for (int i = 0; i < 4; i++) {
      int rowbase = r0 + wr * 64 + i * 16 + quad * 4;
#pragma unroll
      for (int j = 0; j < 4; j++) {
        bf16x4 o;
#pragma unroll
        for (int r = 0; r < 4; r++) o[r] = (__bf16)(acc[i][j][r] * inv4[i][r]);
        *(bf16x4*)(vtp + (size_t)(j * 16 + lc) * T_TOT + rowbase) = o;
      }
    }
  } else {
    __bf16* outp = qkv + ((size_t)(which * NH + h)) * ((size_t)T_TOT * DK);
#pragma unroll
    for (int i = 0; i < 4; i++)
#pragma unroll
      for (int r = 0; r < 4; r++) {
        int row = r0 + wr * 64 + i * 16 + quad * 4 + r;
#pragma unroll
        for (int j = 0; j < 4; j++)
          outp[(size_t)row * DK + j * 16 + lc] = (__bf16)(acc[i][j][r] * inv4[i][r]);
      }
  }
}

// ---------------- flash attention v7: block-cooperative double-buffered LDS staging
__global__ __launch_bounds__(256) void attn_kernel(
    const __bf16* __restrict__ qkv, const __bf16* __restrict__ vt,
    float* __restrict__ out) {
  const int b    = blockIdx.x;          // 0..575
  const int h    = b & 15;
  const int qg   = 35 - (b >> 4);       // 64-row q block, big work first
  const int q0b  = qg * 64;
  const int tid  = threadIdx.x;
  const int wave = tid >> 6, lane = tid & 63;
  const int quad = lane >> 4, lc = lane & 15;
  const int q0w  = q0b + wave * 16;

  const __bf16* qp = qkv + ((size_t)h) * ((size_t)T_TOT * DK);
  const __bf16* kp = qkv + ((size_t)(NH + h)) * ((size_t)T_TOT * DK);
  const __bf16* vp = vt + (size_t)h * (DK * T_TOT);

  __shared__ __bf16 Ks[2][64 * 64];     // [kv][d], swizzled 16B chunks (8/row)
  __shared__ __bf16 Vs[2][64 * 64];     // [d][kv], swizzled
  __shared__ __bf16 Ps[4][16 * 64];     // per-wave P tile

  bf16x8 qf[2];
#pragma unroll
  for (int kk = 0; kk < 2; kk++)
    qf[kk] = *(const bf16x8*)(qp + (size_t)(q0w + lc) * DK + kk * 32 + quad * 8);

  const f32x4 fz = {0.f, 0.f, 0.f, 0.f};
  f32x4 acc_o[4];                       // O^T: d = ct*16+quad*4+r, q = lc
#pragma unroll
  for (int ct = 0; ct < 4; ct++) acc_o[ct] = fz;
  float m_i = -__builtin_inff(), l_i = 0.f;

  const int jstart = (q0b >= SLEN + SEQ) ? 2 : 0;
  const int jend   = qg;

  auto stage = [&](int j, int bufi) {
    const __bf16* kT = kp + (size_t)j * 64 * DK;
#pragma unroll
    for (int it = 0; it < 2; ++it) {
      int L = it * 256 + tid;
      int row = L >> 3, c = (L & 7) ^ (L >> 3 & 7);
      async_copy16(kT + row * DK + c * 8,
                   (char*)&Ks[bufi][0] + (size_t)(it * 256 + wave * 64) * 16);
    }
#pragma unroll
    for (int it = 0; it < 2; ++it) {
      int L = it * 256 + tid;
      int row = L >> 3, c = (L & 7) ^ (L >> 3 & 7);
      async_copy16(vp + (size_t)row * T_TOT + j * 64 + c * 8,
                   (char*)&Vs[bufi][0] + (size_t)(it * 256 + wave * 64) * 16);
    }
  };

  stage(jstart, 0);
  int cur = 0;

  for (int j = jstart; j <= jend; ++j) {
    __syncthreads();
    if (j < jend) stage(j + 1, cur ^ 1);

    const int c0 = j * 64;
    const bool diag = (j == jend);

    f32x4 s[4];
#pragma unroll
    for (int ct = 0; ct < 4; ct++) {
      s[ct] = fz;
#pragma unroll
      for (int kk = 0; kk < 2; kk++) {
        int row = ct * 16 + lc;
        bf16x8 kA = *(const bf16x8*)(&Ks[cur][(row * 8 + (((kk * 4 + quad)) ^ (row & 7))) * 8]);
        s[ct] = __builtin_amdgcn_mfma_f32_16x16x32_bf16(kA, qf[kk], s[ct], 0, 0, 0);
      }
    }

    float mx = -__builtin_inff();
#pragma unroll
    for (int ct = 0; ct < 4; ct++)
#pragma unroll
      for (int r = 0; r < 4; r++) {
        float v = s[ct][r];
        if (diag && (c0 + ct * 16 + quad * 4 + r) > (q0w + lc)) v = -__builtin_inff();
        s[ct][r] = v;
        mx = fmaxf(mx, v);
      }
    mx = fmaxf(mx, __shfl_xor(mx, 16, 64));
    mx = fmaxf(mx, __shfl_xor(mx, 32, 64));
    float mnew  = fmaxf(m_i, mx);
    float alpha = __expf(m_i - mnew);
    float rs = 0.f;
#pragma unroll
    for (int ct = 0; ct < 4; ct++)
#pragma unroll
      for (int r = 0; r < 4; r++) {
        float pe = __expf(s[ct][r] - mnew);
        s[ct][r] = pe;
        rs += pe;
      }
    rs += __shfl_xor(rs, 16, 64);
    rs += __shfl_xor(rs, 32, 64);
    l_i = l_i * alpha + rs;
    m_i = mnew;
#pragma unroll
    for (int ct = 0; ct < 4; ct++)
#pragma unroll
      for (int r = 0; r < 4; r++) acc_o[ct][r] *= alpha;

#pragma unroll
    for (int ct = 0; ct < 4; ct++) {
      bf16x4 pb;
#pragma unroll
      for (int r = 0; r < 4; r++) pb[r] = (__bf16)s[ct][r];
      int cc = ct * 2 + (quad >> 1);
      int el = lc * 64 + ((cc ^ (lc & 7)) * 8) + (quad & 1) * 4;
      *(bf16x4*)(&Ps[wave][el]) = pb;
    }

#pragma unroll
    for (int kq = 0; kq < 2; kq++) {
      int cc = kq * 4 + quad;
      bf16x8 pB = *(const bf16x8*)(&Ps[wave][lc * 64 + ((cc ^ (lc & 7)) * 8)]);
#pragma unroll
      for (int ct = 0; ct < 4; ct++) {
        int vrow = ct * 16 + lc;
        bf16x8 vA = *(const bf16x8*)(&Vs[cur][(vrow * 8 + ((cc) ^ (vrow & 7))) * 8]);
        acc_o[ct] = __builtin_amdgcn_mfma_f32_16x16x32_bf16(vA, pB, acc_o[ct], 0, 0, 0);
      }
    }
    cur ^= 1;
  }

  float invl = 1.0f / l_i;
#pragma unroll
  for (int ct = 0; ct < 4; ct++) {
    f32x4 o;
#pragma unroll
    for (int r = 0; r < 4; r++) o[r] = acc_o[ct][r] * invl;
    *(f32x4*)(&out[((size_t)h * T_TOT + q0w + lc) * DK + ct * 16 + quad * 4]) = o;
  }
}

extern "C" void kernel_launch(void* const* d_in, const int* in_sizes, int n_in,
                              void* d_out, int out_size, void* d_ws, size_t ws_size,
                              hipStream_t stream) {
  const float* x    = (const float*)d_in[0];
  const float* Wq   = (const float*)d_in[1];
  const float* Wk   = (const float*)d_in[2];
  const float* Wv   = (const float*)d_in[3];
  const float* Wqs  = (const float*)d_in[4];
  const float* Wks  = (const float*)d_in[5];
  const float* Wvs  = (const float*)d_in[6];
  const float* scal = (const float*)d_in[7];
  float* out = (float*)d_out;

  char* ws = (char*)d_ws;
  size_t off = 0;
  __bf16* xb  = (__bf16*)(ws + off); off += (size_t)T_TOT * DDIM * 2;
  __bf16* Wt  = (__bf16*)(ws + off); off += (size_t)6 * NH * DK * DDIM * 2;
  __bf16* qkv = (__bf16*)(ws + off); off += (size_t)2 * NH * T_TOT * DK * 2;
  __bf16* vt  = (__bf16*)(ws + off);

  convert_kernel<<<2112, 256, 0, stream>>>(x, Wq, Wk, Wv, Wqs, Wks, Wvs, xb, Wt);
  proj_kernel<<<dim3(8, 18, 3), 256, 0, stream>>>(xb, Wt, scal, qkv, vt);
  attn_kernel<<<dim3(576), 256, 0, stream>>>(qkv, vt, out);
}

// Round 9
// 157.480 us; speedup vs baseline: 1.3418x; 1.0401x over previous
//
#include <hip/hip_runtime.h>
#include <hip/hip_bf16.h>

#define T_TOT 2304
#define DDIM  1024
#define NH    16
#define DK    64
#define SLEN  128
#define SEQ   2048

typedef __bf16 bf16x8 __attribute__((ext_vector_type(8)));
typedef __bf16 bf16x4 __attribute__((ext_vector_type(4)));
typedef float  f32x4  __attribute__((ext_vector_type(4)));

__device__ __forceinline__ void async_copy16(const void* gsrc, void* ldst) {
  __builtin_amdgcn_global_load_lds(
      (const __attribute__((address_space(1))) void*)gsrc,
      (__attribute__((address_space(3))) void*)ldst, 16, 0, 0);
}

// ---------------- convert: x -> bf16 (vectorized); W[h][d][n] -> Wt[m][h][n][d] via LDS transpose
__global__ __launch_bounds__(256) void convert_kernel(
    const float* __restrict__ x,
    const float* __restrict__ Wq, const float* __restrict__ Wk,
    const float* __restrict__ Wv, const float* __restrict__ Wqs,
    const float* __restrict__ Wks, const float* __restrict__ Wvs,
    __bf16* __restrict__ xb, __bf16* __restrict__ Wt) {
  const int b = blockIdx.x;
  const int tid = threadIdx.x;
  if (b < 576) {
    const float4* xin = (const float4*)x;
#pragma unroll
    for (int it = 0; it < 4; ++it) {
      int idx4 = b * 1024 + it * 256 + tid;
      float4 v = xin[idx4];
      bf16x4 o;
      o[0] = (__bf16)v.x; o[1] = (__bf16)v.y; o[2] = (__bf16)v.z; o[3] = (__bf16)v.w;
      *(bf16x4*)(xb + (size_t)idx4 * 4) = o;
    }
    return;
  }
  __shared__ float tile[64 * 65];
  const int wb = b - 576;
  const int m  = wb >> 8;
  const int rem = wb & 255;
  const int h  = rem >> 4;
  const int dt = rem & 15;
  const int d0 = dt * 64;
  const float* Wsrc = (m == 0 ? Wq : m == 1 ? Wk : m == 2 ? Wv
                      : m == 3 ? Wqs : m == 4 ? Wks : Wvs) + (size_t)h * (DDIM * DK);
#pragma unroll
  for (int rr = 0; rr < 4; ++rr) {
    int drow = rr * 16 + (tid >> 4);
    int nc   = (tid & 15) * 4;
    float4 v = *(const float4*)(Wsrc + (size_t)(d0 + drow) * DK + nc);
    tile[(nc + 0) * 65 + drow] = v.x;
    tile[(nc + 1) * 65 + drow] = v.y;
    tile[(nc + 2) * 65 + drow] = v.z;
    tile[(nc + 3) * 65 + drow] = v.w;
  }
  __syncthreads();
  {
    int n  = tid >> 2;
    int rg = (tid & 3) * 16;
    __bf16* dst = Wt + (((size_t)(m * NH + h)) * DK + n) * DDIM + d0 + rg;
    bf16x8 o0, o1;
#pragma unroll
    for (int e = 0; e < 8; e++) o0[e] = (__bf16)tile[n * 65 + rg + e];
#pragma unroll
    for (int e = 0; e < 8; e++) o1[e] = (__bf16)tile[n * 65 + rg + 8 + e];
    *(bf16x8*)dst = o0;
    *(bf16x8*)(dst + 8) = o1;
  }
}

// ---------------- proj v2: m97-shape GEMM 128x128 tile, N=1024 (all 16 heads fused)
// q is pre-scaled by scal[h]*log2(e) so attn softmax can use exp2 directly.
__global__ __launch_bounds__(256) void proj_kernel(
    const __bf16* __restrict__ xb, const __bf16* __restrict__ Wt,
    const float* __restrict__ scal,
    __bf16* __restrict__ qkv, __bf16* __restrict__ vt) {
  const int ntile = blockIdx.x;   // 0..7
  const int rt    = blockIdx.y;   // 0..17
  const int which = blockIdx.z;   // 0=q 1=k 2=v
  const int r0    = rt * 128;
  const int m     = (rt == 0 || rt == 17) ? which + 3 : which;

  __shared__ __bf16 Xs[128 * 64];
  __shared__ __bf16 Wsh[128 * 64];

  const int tid  = threadIdx.x;
  const int wave = tid >> 6, lane = tid & 63;
  const int quad = lane >> 4, lc = lane & 15;
  const int wr   = wave >> 1, wc = wave & 1;
  const int h    = ntile * 2 + wc;

  const __bf16* Wbase = Wt + ((size_t)m * NH) * (DK * DDIM) + (size_t)(ntile * 128) * DDIM;

  const f32x4 fz = {0.f, 0.f, 0.f, 0.f};
  f32x4 acc[4][4];
#pragma unroll
  for (int i = 0; i < 4; i++)
#pragma unroll
    for (int j = 0; j < 4; j++) acc[i][j] = fz;

  for (int k0 = 0; k0 < DDIM; k0 += 64) {
#pragma unroll
    for (int it = 0; it < 4; ++it) {
      int L = it * 256 + tid;
      int row = L >> 3, c = (L & 7) ^ ((L >> 3) & 7);
      async_copy16(xb + (size_t)(r0 + row) * DDIM + k0 + c * 8,
                   (char*)Xs + (size_t)(it * 256 + wave * 64) * 16);
    }
#pragma unroll
    for (int it = 0; it < 4; ++it) {
      int L = it * 256 + tid;
      int row = L >> 3, c = (L & 7) ^ ((L >> 3) & 7);
      async_copy16(Wbase + (size_t)row * DDIM + k0 + c * 8,
                   (char*)Wsh + (size_t)(it * 256 + wave * 64) * 16);
    }
    __syncthreads();
#pragma unroll
    for (int kk = 0; kk < 2; kk++) {
      bf16x8 afr[4], bfr[4];
#pragma unroll
      for (int i = 0; i < 4; i++) {
        int row = wr * 64 + i * 16 + lc;
        int ch  = (kk * 4 + quad) ^ (row & 7);
        afr[i] = *(const bf16x8*)(Xs + (row * 8 + ch) * 8);
      }
#pragma unroll
      for (int j = 0; j < 4; j++) {
        int row = wc * 64 + j * 16 + lc;
        int ch  = (kk * 4 + quad) ^ (row & 7);
        bfr[j] = *(const bf16x8*)(Wsh + (row * 8 + ch) * 8);
      }
#pragma unroll
      for (int i = 0; i < 4; i++)
#pragma unroll
        for (int j = 0; j < 4; j++)
          acc[i][j] = __builtin_amdgcn_mfma_f32_16x16x32_bf16(afr[i], bfr[j], acc[i][j], 0, 0, 0);
    }
    __syncthreads();
  }

  const float qscale = (which == 0) ? scal[h] * 1.44269504088896f : 1.0f;
  float inv4[4][4];
#pragma unroll
  for (int i = 0; i < 4; i++) {
#pragma unroll
    for (int r = 0; r < 4; r++) {
      float s = 0.f;
#pragma unroll
      for (int j = 0; j < 4; j++) { float v = acc[i][j][r]; s += v * v; }
#pragma unroll
      for (int off = 1; off < 16; off <<= 1) s += __shfl_xor(s, off, 64);
      inv4[i][r] = qscale / fmaxf(sqrtf(s), 1e-12f);
    }
  }
  if (which == 2) {
    __bf16* vtp = vt + (size_t)h * (DK * T_TOT);
#pragma unroll
    for (int i = 0; i < 4; i++) {
      int rowbase = r0 + wr * 64 + i * 16 + quad * 4;
#pragma unroll
      for (int j = 0; j < 4; j++) {
        bf16x4 o;
#pragma unroll
        for (int r = 0; r < 4; r++) o[r] = (__bf16)(acc[i][j][r] * inv4[i][r]);
        *(bf16x4*)(vtp + (size_t)(j * 16 + lc) * T_TOT + rowbase) = o;
      }
    }
  } else {
    __bf16* outp = qkv + ((size_t)(which * NH + h)) * ((size_t)T_TOT * DK);
#pragma unroll
    for (int i = 0; i < 4; i++)
#pragma unroll
      for (int r = 0; r < 4; r++) {
        int row = r0 + wr * 64 + i * 16 + quad * 4 + r;
#pragma unroll
        for (int j = 0; j < 4; j++)
          outp[(size_t)row * DK + j * 16 + lc] = (__bf16)(acc[i][j][r] * inv4[i][r]);
      }
  }
}

// ---------------- flash attention v8: BN=128 double-buffered LDS staging, exp2 softmax
// Block = 4 waves x 16 q-rows (BM=64); K/V via global_load_lds; 1 barrier per 128-kv tile.
__global__ __launch_bounds__(256) void attn_kernel(
    const __bf16* __restrict__ qkv, const __bf16* __restrict__ vt,
    float* __restrict__ out) {
  const int b    = blockIdx.x;          // 0..575
  const int h    = b & 15;
  const int qg   = 35 - (b >> 4);       // 64-row q block, big work first
  const int q0b  = qg * 64;
  const int tid  = threadIdx.x;
  const int wave = tid >> 6, lane = tid & 63;
  const int quad = lane >> 4, lc = lane & 15;
  const int q0w  = q0b + wave * 16;

  const __bf16* qp = qkv + ((size_t)h) * ((size_t)T_TOT * DK);
  const __bf16* kp = qkv + ((size_t)(NH + h)) * ((size_t)T_TOT * DK);
  const __bf16* vp = vt + (size_t)h * (DK * T_TOT);

  __shared__ __bf16 Ks[2][128 * 64];    // [kv][d-chunks swizzled]  32 KB
  __shared__ __bf16 Vs[2][64 * 128];    // [d][kv-chunks swizzled]  32 KB
  __shared__ __bf16 Ps[4][16 * 128];    // per-wave P [q][kv]       16 KB

  bf16x8 qf[2];
#pragma unroll
  for (int kk = 0; kk < 2; kk++)
    qf[kk] = *(const bf16x8*)(qp + (size_t)(q0w + lc) * DK + kk * 32 + quad * 8);

  const f32x4 fz = {0.f, 0.f, 0.f, 0.f};
  f32x4 acc_o[4];                       // O^T: d = ct*16+quad*4+r, q = lc
#pragma unroll
  for (int ct = 0; ct < 4; ct++) acc_o[ct] = fz;
  float m_i = -__builtin_inff(), l_i = 0.f;

  const int jstart = (q0b >= SLEN + SEQ) ? 1 : 0;   // 128-kv tiles
  const int jend   = q0b >> 7;

  auto stage = [&](int j, int bufi) {
    const __bf16* kT = kp + (size_t)j * 128 * DK;
#pragma unroll
    for (int it = 0; it < 4; ++it) {
      int L = it * 256 + tid;
      int row = L >> 3, c = (L & 7) ^ ((L >> 3) & 7);
      async_copy16(kT + row * DK + c * 8,
                   (char*)&Ks[bufi][0] + (size_t)(it * 256 + wave * 64) * 16);
    }
#pragma unroll
    for (int it = 0; it < 4; ++it) {
      int L = it * 256 + tid;
      int d = L >> 4, c = (L & 15) ^ ((L >> 4) & 15);
      async_copy16(vp + (size_t)d * T_TOT + j * 128 + c * 8,
                   (char*)&Vs[bufi][0] + (size_t)(it * 256 + wave * 64) * 16);
    }
  };

  stage(jstart, 0);
  int cur = 0;

  for (int j = jstart; j <= jend; ++j) {
    __syncthreads();                    // drains buf-cur loads + joins waves
    if (j < jend) stage(j + 1, cur ^ 1);

    const int c0 = j * 128;
    const bool diag = (j == jend);
    const int ctmax = diag ? ((q0b & 64) ? 7 : 3) : 7;

    // S^T = K Q^T over 128 kv: C[kv=ct*16+quad*4+r][q=lc]
    f32x4 s[8];
#pragma unroll
    for (int ct = 0; ct < 8; ct++) {
      s[ct] = fz;
      if (ct <= ctmax) {
#pragma unroll
        for (int kk = 0; kk < 2; kk++) {
          int row = ct * 16 + lc;
          bf16x8 kA = *(const bf16x8*)(&Ks[cur][(row * 8 + ((kk * 4 + quad) ^ (row & 7))) * 8]);
          s[ct] = __builtin_amdgcn_mfma_f32_16x16x32_bf16(kA, qf[kk], s[ct], 0, 0, 0);
        }
      }
    }

    // softmax (log2 domain; q pre-scaled by scale*log2e)
    float mx = -__builtin_inff();
    if (diag) {
#pragma unroll
      for (int ct = 0; ct < 8; ct++) {
        if (ct > ctmax) break;
#pragma unroll
        for (int r = 0; r < 4; r++) {
          float v = s[ct][r];
          if ((c0 + ct * 16 + quad * 4 + r) > (q0w + lc)) v = -__builtin_inff();
          s[ct][r] = v;
          mx = fmaxf(mx, v);
        }
      }
    } else {
#pragma unroll
      for (int ct = 0; ct < 8; ct++)
#pragma unroll
        for (int r = 0; r < 4; r++) mx = fmaxf(mx, s[ct][r]);
    }
    mx = fmaxf(mx, __shfl_xor(mx, 16, 64));
    mx = fmaxf(mx, __shfl_xor(mx, 32, 64));
    float mnew  = fmaxf(m_i, mx);
    float alpha = exp2f(m_i - mnew);
    float rs = 0.f;
#pragma unroll
    for (int ct = 0; ct < 8; ct++) {
      if (ct > ctmax) break;
#pragma unroll
      for (int r = 0; r < 4; r++) {
        float pe = exp2f(s[ct][r] - mnew);
        s[ct][r] = pe;
        rs += pe;
      }
    }
    rs += __shfl_xor(rs, 16, 64);
    rs += __shfl_xor(rs, 32, 64);
    l_i = l_i * alpha + rs;
    m_i = mnew;
#pragma unroll
    for (int ct = 0; ct < 4; ct++)
#pragma unroll
      for (int r = 0; r < 4; r++) acc_o[ct][r] *= alpha;

    // write P to wave-local LDS: [q=lc][kv], chunk swizzle cc' = cc ^ (lc&15)
#pragma unroll
    for (int ct = 0; ct < 8; ct++) {
      if (ct > ctmax) break;
      bf16x4 pb;
#pragma unroll
      for (int r = 0; r < 4; r++) pb[r] = (__bf16)s[ct][r];
      int cc = ct * 2 + (quad >> 1);
      int el = lc * 128 + ((cc ^ (lc & 15)) * 8) + (quad & 1) * 4;
      *(bf16x4*)(&Ps[wave][el]) = pb;
    }

    // O^T += V^T P^T : A = V^T rows from LDS, B = P (wave-local LDS)
    const int kqmax = diag ? ((q0b & 64) ? 3 : 1) : 3;
#pragma unroll
    for (int kq = 0; kq < 4; kq++) {
      if (kq > kqmax) break;
      int cc = kq * 4 + quad;
      bf16x8 pB = *(const bf16x8*)(&Ps[wave][lc * 128 + ((cc ^ (lc & 15)) * 8)]);
#pragma unroll
      for (int ct = 0; ct < 4; ct++) {
        int d = ct * 16 + lc;
        bf16x8 vA = *(const bf16x8*)(&Vs[cur][(d * 16 + (cc ^ (d & 15))) * 8]);
        acc_o[ct] = __builtin_amdgcn_mfma_f32_16x16x32_bf16(vA, pB, acc_o[ct], 0, 0, 0);
      }
    }
    cur ^= 1;
  }

  float invl = 1.0f / l_i;
#pragma unroll
  for (int ct = 0; ct < 4; ct++) {
    f32x4 o;
#pragma unroll
    for (int r = 0; r < 4; r++) o[r] = acc_o[ct][r] * invl;
    *(f32x4*)(&out[((size_t)h * T_TOT + q0w + lc) * DK + ct * 16 + quad * 4]) = o;
  }
}

extern "C" void kernel_launch(void* const* d_in, const int* in_sizes, int n_in,
                              void* d_out, int out_size, void* d_ws, size_t ws_size,
                              hipStream_t stream) {
  const float* x    = (const float*)d_in[0];
  const float* Wq   = (const float*)d_in[1];
  const float* Wk   = (const float*)d_in[2];
  const float* Wv   = (const float*)d_in[3];
  const float* Wqs  = (const float*)d_in[4];
  const float* Wks  = (const float*)d_in[5];
  const float* Wvs  = (const float*)d_in[6];
  const float* scal = (const float*)d_in[7];
  float* out = (float*)d_out;

  char* ws = (char*)d_ws;
  size_t off = 0;
  __bf16* xb  = (__bf16*)(ws + off); off += (size_t)T_TOT * DDIM * 2;
  __bf16* Wt  = (__bf16*)(ws + off); off += (size_t)6 * NH * DK * DDIM * 2;
  __bf16* qkv = (__bf16*)(ws + off); off += (size_t)2 * NH * T_TOT * DK * 2;
  __bf16* vt  = (__bf16*)(ws + off);

  convert_kernel<<<2112, 256, 0, stream>>>(x, Wq, Wk, Wv, Wqs, Wks, Wvs, xb, Wt);
  proj_kernel<<<dim3(8, 18, 3), 256, 0, stream>>>(xb, Wt, scal, qkv, vt);
  attn_kernel<<<dim3(576), 256, 0, stream>>>(qkv, vt, out);
}

// Round 10
// 155.759 us; speedup vs baseline: 1.3567x; 1.0110x over previous
//
#include <hip/hip_runtime.h>
#include <hip/hip_bf16.h>

#define T_TOT 2304
#define DDIM  1024
#define NH    16
#define DK    64
#define SLEN  128
#define SEQ   2048

typedef __bf16 bf16x8 __attribute__((ext_vector_type(8)));
typedef __bf16 bf16x4 __attribute__((ext_vector_type(4)));
typedef float  f32x4  __attribute__((ext_vector_type(4)));

__device__ __forceinline__ void async_copy16(const void* gsrc, void* ldst) {
  __builtin_amdgcn_global_load_lds(
      (const __attribute__((address_space(1))) void*)gsrc,
      (__attribute__((address_space(3))) void*)ldst, 16, 0, 0);
}

// ---------------- convert: x -> bf16 (vectorized); W[h][d][n] -> Wt[m][h][n][d] via LDS transpose
__global__ __launch_bounds__(256) void convert_kernel(
    const float* __restrict__ x,
    const float* __restrict__ Wq, const float* __restrict__ Wk,
    const float* __restrict__ Wv, const float* __restrict__ Wqs,
    const float* __restrict__ Wks, const float* __restrict__ Wvs,
    __bf16* __restrict__ xb, __bf16* __restrict__ Wt) {
  const int b = blockIdx.x;
  const int tid = threadIdx.x;
  if (b < 576) {
    const float4* xin = (const float4*)x;
#pragma unroll
    for (int it = 0; it < 4; ++it) {
      int idx4 = b * 1024 + it * 256 + tid;
      float4 v = xin[idx4];
      bf16x4 o;
      o[0] = (__bf16)v.x; o[1] = (__bf16)v.y; o[2] = (__bf16)v.z; o[3] = (__bf16)v.w;
      *(bf16x4*)(xb + (size_t)idx4 * 4) = o;
    }
    return;
  }
  __shared__ float tile[64 * 65];
  const int wb = b - 576;
  const int m  = wb >> 8;
  const int rem = wb & 255;
  const int h  = rem >> 4;
  const int dt = rem & 15;
  const int d0 = dt * 64;
  const float* Wsrc = (m == 0 ? Wq : m == 1 ? Wk : m == 2 ? Wv
                      : m == 3 ? Wqs : m == 4 ? Wks : Wvs) + (size_t)h * (DDIM * DK);
#pragma unroll
  for (int rr = 0; rr < 4; ++rr) {
    int drow = rr * 16 + (tid >> 4);
    int nc   = (tid & 15) * 4;
    float4 v = *(const float4*)(Wsrc + (size_t)(d0 + drow) * DK + nc);
    tile[(nc + 0) * 65 + drow] = v.x;
    tile[(nc + 1) * 65 + drow] = v.y;
    tile[(nc + 2) * 65 + drow] = v.z;
    tile[(nc + 3) * 65 + drow] = v.w;
  }
  __syncthreads();
  {
    int n  = tid >> 2;
    int rg = (tid & 3) * 16;
    __bf16* dst = Wt + (((size_t)(m * NH + h)) * DK + n) * DDIM + d0 + rg;
    bf16x8 o0, o1;
#pragma unroll
    for (int e = 0; e < 8; e++) o0[e] = (__bf16)tile[n * 65 + rg + e];
#pragma unroll
    for (int e = 0; e < 8; e++) o1[e] = (__bf16)tile[n * 65 + rg + 8 + e];
    *(bf16x8*)dst = o0;
    *(bf16x8*)(dst + 8) = o1;
  }
}

// ---------------- proj v2: m97-shape GEMM 128x128 tile, N=1024 (all 16 heads fused)
// q is pre-scaled by scal[h]*log2(e) so attn softmax can use exp2 directly.
__global__ __launch_bounds__(256) void proj_kernel(
    const __bf16* __restrict__ xb, const __bf16* __restrict__ Wt,
    const float* __restrict__ scal,
    __bf16* __restrict__ qkv, __bf16* __restrict__ vt) {
  const int ntile = blockIdx.x;   // 0..7
  const int rt    = blockIdx.y;   // 0..17
  const int which = blockIdx.z;   // 0=q 1=k 2=v
  const int r0    = rt * 128;
  const int m     = (rt == 0 || rt == 17) ? which + 3 : which;

  __shared__ __bf16 Xs[128 * 64];
  __shared__ __bf16 Wsh[128 * 64];

  const int tid  = threadIdx.x;
  const int wave = tid >> 6, lane = tid & 63;
  const int quad = lane >> 4, lc = lane & 15;
  const int wr   = wave >> 1, wc = wave & 1;
  const int h    = ntile * 2 + wc;

  const __bf16* Wbase = Wt + ((size_t)m * NH) * (DK * DDIM) + (size_t)(ntile * 128) * DDIM;

  const f32x4 fz = {0.f, 0.f, 0.f, 0.f};
  f32x4 acc[4][4];
#pragma unroll
  for (int i = 0; i < 4; i++)
#pragma unroll
    for (int j = 0; j < 4; j++) acc[i][j] = fz;

  for (int k0 = 0; k0 < DDIM; k0 += 64) {
#pragma unroll
    for (int it = 0; it < 4; ++it) {
      int L = it * 256 + tid;
      int row = L >> 3, c = (L & 7) ^ ((L >> 3) & 7);
      async_copy16(xb + (size_t)(r0 + row) * DDIM + k0 + c * 8,
                   (char*)Xs + (size_t)(it * 256 + wave * 64) * 16);
    }
#pragma unroll
    for (int it = 0; it < 4; ++it) {
      int L = it * 256 + tid;
      int row = L >> 3, c = (L & 7) ^ ((L >> 3) & 7);
      async_copy16(Wbase + (size_t)row * DDIM + k0 + c * 8,
                   (char*)Wsh + (size_t)(it * 256 + wave * 64) * 16);
    }
    __syncthreads();
#pragma unroll
    for (int kk = 0; kk < 2; kk++) {
      bf16x8 afr[4], bfr[4];
#pragma unroll
      for (int i = 0; i < 4; i++) {
        int row = wr * 64 + i * 16 + lc;
        int ch  = (kk * 4 + quad) ^ (row & 7);
        afr[i] = *(const bf16x8*)(Xs + (row * 8 + ch) * 8);
      }
#pragma unroll
      for (int j = 0; j < 4; j++) {
        int row = wc * 64 + j * 16 + lc;
        int ch  = (kk * 4 + quad) ^ (row & 7);
        bfr[j] = *(const bf16x8*)(Wsh + (row * 8 + ch) * 8);
      }
#pragma unroll
      for (int i = 0; i < 4; i++)
#pragma unroll
        for (int j = 0; j < 4; j++)
          acc[i][j] = __builtin_amdgcn_mfma_f32_16x16x32_bf16(afr[i], bfr[j], acc[i][j], 0, 0, 0);
    }
    __syncthreads();
  }

  const float qscale = (which == 0) ? scal[h] * 1.44269504088896f : 1.0f;
  float inv4[4][4];
#pragma unroll
  for (int i = 0; i < 4; i++) {
#pragma unroll
    for (int r = 0; r < 4; r++) {
      float s = 0.f;
#pragma unroll
      for (int j = 0; j < 4; j++) { float v = acc[i][j][r]; s += v * v; }
#pragma unroll
      for (int off = 1; off < 16; off <<= 1) s += __shfl_xor(s, off, 64);
      inv4[i][r] = qscale / fmaxf(sqrtf(s), 1e-12f);
    }
  }
  if (which == 2) {
    __bf16* vtp = vt + (size_t)h * (DK * T_TOT);
#pragma unroll
    for (int i = 0; i < 4; i++) {
      int rowbase = r0 + wr * 64 + i * 16 + quad * 4;
#pragma unroll
      for (int j = 0; j < 4; j++) {
        bf16x4 o;
#pragma unroll
        for (int r = 0; r < 4; r++) o[r] = (__bf16)(acc[i][j][r] * inv4[i][r]);
        *(bf16x4*)(vtp + (size_t)(j * 16 + lc) * T_TOT + rowbase) = o;
      }
    }
  } else {
    __bf16* outp = qkv + ((size_t)(which * NH + h)) * ((size_t)T_TOT * DK);
#pragma unroll
    for (int i = 0; i < 4; i++)
#pragma unroll
      for (int r = 0; r < 4; r++) {
        int row = r0 + wr * 64 + i * 16 + quad * 4 + r;
#pragma unroll
        for (int j = 0; j < 4; j++)
          outp[(size_t)row * DK + j * 16 + lc] = (__bf16)(acc[i][j][r] * inv4[i][r]);
      }
  }
}

// ---------------- flash attention v9: fixed-shift softmax (q,k are l2-normed ->
// scores bounded, shift M=0 is exact). NO online max, NO rescale, NO cross-lane
// ops in the kv loop; l reduced once at the end. BN=128 double-buffered staging.
__global__ __launch_bounds__(256) void attn_kernel(
    const __bf16* __restrict__ qkv, const __bf16* __restrict__ vt,
    float* __restrict__ out) {
  const int b    = blockIdx.x;          // 0..575
  const int h    = b & 15;
  const int qg   = 35 - (b >> 4);       // 64-row q block, big work first
  const int q0b  = qg * 64;
  const int tid  = threadIdx.x;
  const int wave = tid >> 6, lane = tid & 63;
  const int quad = lane >> 4, lc = lane & 15;
  const int q0w  = q0b + wave * 16;

  const __bf16* qp = qkv + ((size_t)h) * ((size_t)T_TOT * DK);
  const __bf16* kp = qkv + ((size_t)(NH + h)) * ((size_t)T_TOT * DK);
  const __bf16* vp = vt + (size_t)h * (DK * T_TOT);

  __shared__ __bf16 Ks[2][128 * 64];    // [kv][d-chunks swizzled]  32 KB
  __shared__ __bf16 Vs[2][64 * 128];    // [d][kv-chunks swizzled]  32 KB
  __shared__ __bf16 Ps[4][16 * 128];    // per-wave P [q][kv]       16 KB

  bf16x8 qf[2];
#pragma unroll
  for (int kk = 0; kk < 2; kk++)
    qf[kk] = *(const bf16x8*)(qp + (size_t)(q0w + lc) * DK + kk * 32 + quad * 8);

  const f32x4 fz = {0.f, 0.f, 0.f, 0.f};
  f32x4 acc_o[4];                       // O^T: d = ct*16+quad*4+r, q = lc
#pragma unroll
  for (int ct = 0; ct < 4; ct++) acc_o[ct] = fz;
  float l_part = 0.f;                   // per-lane partial row sum (reduced at end)

  const int jstart = (q0b >= SLEN + SEQ) ? 1 : 0;   // 128-kv tiles
  const int jend   = q0b >> 7;

  auto stage = [&](int j, int bufi) {
    const __bf16* kT = kp + (size_t)j * 128 * DK;
#pragma unroll
    for (int it = 0; it < 4; ++it) {
      int L = it * 256 + tid;
      int row = L >> 3, c = (L & 7) ^ ((L >> 3) & 7);
      async_copy16(kT + row * DK + c * 8,
                   (char*)&Ks[bufi][0] + (size_t)(it * 256 + wave * 64) * 16);
    }
#pragma unroll
    for (int it = 0; it < 4; ++it) {
      int L = it * 256 + tid;
      int d = L >> 4, c = (L & 15) ^ ((L >> 4) & 15);
      async_copy16(vp + (size_t)d * T_TOT + j * 128 + c * 8,
                   (char*)&Vs[bufi][0] + (size_t)(it * 256 + wave * 64) * 16);
    }
  };

  stage(jstart, 0);
  int cur = 0;

  for (int j = jstart; j <= jend; ++j) {
    __syncthreads();                    // drains buf-cur loads + joins waves
    if (j < jend) stage(j + 1, cur ^ 1);

    const int c0 = j * 128;
    const bool diag = (j == jend);
    const int ctmax = diag ? ((q0b & 64) ? 7 : 3) : 7;

    // S^T = K Q^T over 128 kv: C[kv=ct*16+quad*4+r][q=lc]
    f32x4 s[8];
#pragma unroll
    for (int ct = 0; ct < 8; ct++) {
      s[ct] = fz;
      if (ct <= ctmax) {
#pragma unroll
        for (int kk = 0; kk < 2; kk++) {
          int row = ct * 16 + lc;
          bf16x8 kA = *(const bf16x8*)(&Ks[cur][(row * 8 + ((kk * 4 + quad) ^ (row & 7))) * 8]);
          s[ct] = __builtin_amdgcn_mfma_f32_16x16x32_bf16(kA, qf[kk], s[ct], 0, 0, 0);
        }
      }
    }

    // fixed-shift softmax: p = exp2(s) directly (scores bounded ~|0.19|);
    // masked entries -> -inf -> exp2 = 0. No cross-lane ops here.
#pragma unroll
    for (int ct = 0; ct < 8; ct++) {
      if (ct > ctmax) break;
      if (diag) {
#pragma unroll
        for (int r = 0; r < 4; r++)
          if ((c0 + ct * 16 + quad * 4 + r) > (q0w + lc)) s[ct][r] = -__builtin_inff();
      }
      bf16x4 pb;
#pragma unroll
      for (int r = 0; r < 4; r++) {
        float pe = exp2f(s[ct][r]);
        l_part += pe;
        pb[r] = (__bf16)pe;
      }
      int cc = ct * 2 + (quad >> 1);
      int el = lc * 128 + ((cc ^ (lc & 15)) * 8) + (quad & 1) * 4;
      *(bf16x4*)(&Ps[wave][el]) = pb;
    }

    // O^T += V^T P^T : A = V^T rows from LDS, B = P (wave-local LDS)
    const int kqmax = diag ? ((q0b & 64) ? 3 : 1) : 3;
#pragma unroll
    for (int kq = 0; kq < 4; kq++) {
      if (kq > kqmax) break;
      int cc = kq * 4 + quad;
      bf16x8 pB = *(const bf16x8*)(&Ps[wave][lc * 128 + ((cc ^ (lc & 15)) * 8)]);
#pragma unroll
      for (int ct = 0; ct < 4; ct++) {
        int d = ct * 16 + lc;
        bf16x8 vA = *(const bf16x8*)(&Vs[cur][(d * 16 + (cc ^ (d & 15))) * 8]);
        acc_o[ct] = __builtin_amdgcn_mfma_f32_16x16x32_bf16(vA, pB, acc_o[ct], 0, 0, 0);
      }
    }
    cur ^= 1;
  }

  // single end-of-loop row-sum reduction (kv distributed across quads)
  float l_i = l_part;
  l_i += __shfl_xor(l_i, 16, 64);
  l_i += __shfl_xor(l_i, 32, 64);
  float invl = 1.0f / l_i;
#pragma unroll
  for (int ct = 0; ct < 4; ct++) {
    f32x4 o;
#pragma unroll
    for (int r = 0; r < 4; r++) o[r] = acc_o[ct][r] * invl;
    *(f32x4*)(&out[((size_t)h * T_TOT + q0w + lc) * DK + ct * 16 + quad * 4]) = o;
  }
}

extern "C" void kernel_launch(void* const* d_in, const int* in_sizes, int n_in,
                              void* d_out, int out_size, void* d_ws, size_t ws_size,
                              hipStream_t stream) {
  const float* x    = (const float*)d_in[0];
  const float* Wq   = (const float*)d_in[1];
  const float* Wk   = (const float*)d_in[2];
  const float* Wv   = (const float*)d_in[3];
  const float* Wqs  = (const float*)d_in[4];
  const float* Wks  = (const float*)d_in[5];
  const float* Wvs  = (const float*)d_in[6];
  const float* scal = (const float*)d_in[7];
  float* out = (float*)d_out;

  char* ws = (char*)d_ws;
  size_t off = 0;
  __bf16* xb  = (__bf16*)(ws + off); off += (size_t)T_TOT * DDIM * 2;
  __bf16* Wt  = (__bf16*)(ws + off); off += (size_t)6 * NH * DK * DDIM * 2;
  __bf16* qkv = (__bf16*)(ws + off); off += (size_t)2 * NH * T_TOT * DK * 2;
  __bf16* vt  = (__bf16*)(ws + off);

  convert_kernel<<<2112, 256, 0, stream>>>(x, Wq, Wk, Wv, Wqs, Wks, Wvs, xb, Wt);
  proj_kernel<<<dim3(8, 18, 3), 256, 0, stream>>>(xb, Wt, scal, qkv, vt);
  attn_kernel<<<dim3(576), 256, 0, stream>>>(qkv, vt, out);
}

// Round 11
// 155.716 us; speedup vs baseline: 1.3570x; 1.0003x over previous
//
#include <hip/hip_runtime.h>
#include <hip/hip_bf16.h>

#define T_TOT 2304
#define DDIM  1024
#define NH    16
#define DK    64
#define SLEN  128
#define SEQ   2048

typedef __bf16 bf16x8 __attribute__((ext_vector_type(8)));
typedef __bf16 bf16x4 __attribute__((ext_vector_type(4)));
typedef float  f32x4  __attribute__((ext_vector_type(4)));
typedef float  f32x16 __attribute__((ext_vector_type(16)));

__device__ __forceinline__ void async_copy16(const void* gsrc, void* ldst) {
  __builtin_amdgcn_global_load_lds(
      (const __attribute__((address_space(1))) void*)gsrc,
      (__attribute__((address_space(3))) void*)ldst, 16, 0, 0);
}

// LDS-only barrier: waits own LDS ops, joins waves, does NOT drain vmcnt
// (keeps global_load_lds prefetch in flight across the barrier).
__device__ __forceinline__ void lds_barrier() {
  __asm__ volatile("s_waitcnt lgkmcnt(0)\n\ts_barrier" ::: "memory");
}

// ---------------- convert: x -> bf16 (vectorized); W[h][d][n] -> Wt[m][h][n][d] via LDS transpose
__global__ __launch_bounds__(256) void convert_kernel(
    const float* __restrict__ x,
    const float* __restrict__ Wq, const float* __restrict__ Wk,
    const float* __restrict__ Wv, const float* __restrict__ Wqs,
    const float* __restrict__ Wks, const float* __restrict__ Wvs,
    __bf16* __restrict__ xb, __bf16* __restrict__ Wt) {
  const int b = blockIdx.x;
  const int tid = threadIdx.x;
  if (b < 576) {
    const float4* xin = (const float4*)x;
#pragma unroll
    for (int it = 0; it < 4; ++it) {
      int idx4 = b * 1024 + it * 256 + tid;
      float4 v = xin[idx4];
      bf16x4 o;
      o[0] = (__bf16)v.x; o[1] = (__bf16)v.y; o[2] = (__bf16)v.z; o[3] = (__bf16)v.w;
      *(bf16x4*)(xb + (size_t)idx4 * 4) = o;
    }
    return;
  }
  __shared__ float tile[64 * 65];
  const int wb = b - 576;
  const int m  = wb >> 8;
  const int rem = wb & 255;
  const int h  = rem >> 4;
  const int dt = rem & 15;
  const int d0 = dt * 64;
  const float* Wsrc = (m == 0 ? Wq : m == 1 ? Wk : m == 2 ? Wv
                      : m == 3 ? Wqs : m == 4 ? Wks : Wvs) + (size_t)h * (DDIM * DK);
#pragma unroll
  for (int rr = 0; rr < 4; ++rr) {
    int drow = rr * 16 + (tid >> 4);
    int nc   = (tid & 15) * 4;
    float4 v = *(const float4*)(Wsrc + (size_t)(d0 + drow) * DK + nc);
    tile[(nc + 0) * 65 + drow] = v.x;
    tile[(nc + 1) * 65 + drow] = v.y;
    tile[(nc + 2) * 65 + drow] = v.z;
    tile[(nc + 3) * 65 + drow] = v.w;
  }
  __syncthreads();
  {
    int n  = tid >> 2;
    int rg = (tid & 3) * 16;
    __bf16* dst = Wt + (((size_t)(m * NH + h)) * DK + n) * DDIM + d0 + rg;
    bf16x8 o0, o1;
#pragma unroll
    for (int e = 0; e < 8; e++) o0[e] = (__bf16)tile[n * 65 + rg + e];
#pragma unroll
    for (int e = 0; e < 8; e++) o1[e] = (__bf16)tile[n * 65 + rg + 8 + e];
    *(bf16x8*)dst = o0;
    *(bf16x8*)(dst + 8) = o1;
  }
}

// ---------------- proj v2: m97-shape GEMM 128x128 tile, N=1024 (all 16 heads fused)
// q is pre-scaled by scal[h]*log2(e) so attn softmax can use exp2 directly.
__global__ __launch_bounds__(256) void proj_kernel(
    const __bf16* __restrict__ xb, const __bf16* __restrict__ Wt,
    const float* __restrict__ scal,
    __bf16* __restrict__ qkv, __bf16* __restrict__ vt) {
  const int ntile = blockIdx.x;   // 0..7
  const int rt    = blockIdx.y;   // 0..17
  const int which = blockIdx.z;   // 0=q 1=k 2=v
  const int r0    = rt * 128;
  const int m     = (rt == 0 || rt == 17) ? which + 3 : which;

  __shared__ __bf16 Xs[128 * 64];
  __shared__ __bf16 Wsh[128 * 64];

  const int tid  = threadIdx.x;
  const int wave = tid >> 6, lane = tid & 63;
  const int quad = lane >> 4, lc = lane & 15;
  const int wr   = wave >> 1, wc = wave & 1;
  const int h    = ntile * 2 + wc;

  const __bf16* Wbase = Wt + ((size_t)m * NH) * (DK * DDIM) + (size_t)(ntile * 128) * DDIM;

  const f32x4 fz = {0.f, 0.f, 0.f, 0.f};
  f32x4 acc[4][4];
#pragma unroll
  for (int i = 0; i < 4; i++)
#pragma unroll
    for (int j = 0; j < 4; j++) acc[i][j] = fz;

  for (int k0 = 0; k0 < DDIM; k0 += 64) {
#pragma unroll
    for (int it = 0; it < 4; ++it) {
      int L = it * 256 + tid;
      int row = L >> 3, c = (L & 7) ^ ((L >> 3) & 7);
      async_copy16(xb + (size_t)(r0 + row) * DDIM + k0 + c * 8,
                   (char*)Xs + (size_t)(it * 256 + wave * 64) * 16);
    }
#pragma unroll
    for (int it = 0; it < 4; ++it) {
      int L = it * 256 + tid;
      int row = L >> 3, c = (L & 7) ^ ((L >> 3) & 7);
      async_copy16(Wbase + (size_t)row * DDIM + k0 + c * 8,
                   (char*)Wsh + (size_t)(it * 256 + wave * 64) * 16);
    }
    __syncthreads();
#pragma unroll
    for (int kk = 0; kk < 2; kk++) {
      bf16x8 afr[4], bfr[4];
#pragma unroll
      for (int i = 0; i < 4; i++) {
        int row = wr * 64 + i * 16 + lc;
        int ch  = (kk * 4 + quad) ^ (row & 7);
        afr[i] = *(const bf16x8*)(Xs + (row * 8 + ch) * 8);
      }
#pragma unroll
      for (int j = 0; j < 4; j++) {
        int row = wc * 64 + j * 16 + lc;
        int ch  = (kk * 4 + quad) ^ (row & 7);
        bfr[j] = *(const bf16x8*)(Wsh + (row * 8 + ch) * 8);
      }
#pragma unroll
      for (int i = 0; i < 4; i++)
#pragma unroll
        for (int j = 0; j < 4; j++)
          acc[i][j] = __builtin_amdgcn_mfma_f32_16x16x32_bf16(afr[i], bfr[j], acc[i][j], 0, 0, 0);
    }
    __syncthreads();
  }

  const float qscale = (which == 0) ? scal[h] * 1.44269504088896f : 1.0f;
  float inv4[4][4];
#pragma unroll
  for (int i = 0; i < 4; i++) {
#pragma unroll
    for (int r = 0; r < 4; r++) {
      float s = 0.f;
#pragma unroll
      for (int j = 0; j < 4; j++) { float v = acc[i][j][r]; s += v * v; }
#pragma unroll
      for (int off = 1; off < 16; off <<= 1) s += __shfl_xor(s, off, 64);
      inv4[i][r] = qscale / fmaxf(sqrtf(s), 1e-12f);
    }
  }
  if (which == 2) {
    __bf16* vtp = vt + (size_t)h * (DK * T_TOT);
#pragma unroll
    for (int i = 0; i < 4; i++) {
      int rowbase = r0 + wr * 64 + i * 16 + quad * 4;
#pragma unroll
      for (int j = 0; j < 4; j++) {
        bf16x4 o;
#pragma unroll
        for (int r = 0; r < 4; r++) o[r] = (__bf16)(acc[i][j][r] * inv4[i][r]);
        *(bf16x4*)(vtp + (size_t)(j * 16 + lc) * T_TOT + rowbase) = o;
      }
    }
  } else {
    __bf16* outp = qkv + ((size_t)(which * NH + h)) * ((size_t)T_TOT * DK);
#pragma unroll
    for (int i = 0; i < 4; i++)
#pragma unroll
      for (int r = 0; r < 4; r++) {
        int row = r0 + wr * 64 + i * 16 + quad * 4 + r;
#pragma unroll
        for (int j = 0; j < 4; j++)
          outp[(size_t)row * DK + j * 16 + lc] = (__bf16)(acc[i][j][r] * inv4[i][r]);
      }
  }
}

// ---------------- flash attention v10: kv-sliced S (Q in regs), 32x32x16 PV,
// fixed-shift softmax. LDS instr per wave per 64-kv tile: 2 (S) + 4 (P-wr) + 8 (PV).
// Two barriers/iter; the mid barrier is LDS-only (prefetch stays in flight).
__global__ __launch_bounds__(256, 3) void attn_kernel(
    const __bf16* __restrict__ qkv, const __bf16* __restrict__ vt,
    float* __restrict__ out) {
  const int b    = blockIdx.x;          // 0..575
  const int h    = b & 15;
  const int qg   = 35 - (b >> 4);       // 64-row q block, big work first
  const int q0b  = qg * 64;
  const int tid  = threadIdx.x;
  const int wave = tid >> 6, lane = tid & 63;
  const int quad = lane >> 4, lc = lane & 15;
  const int l32  = lane & 31, hi = lane >> 5;

  const __bf16* qp = qkv + ((size_t)h) * ((size_t)T_TOT * DK);
  const __bf16* kp = qkv + ((size_t)(NH + h)) * ((size_t)T_TOT * DK);
  const __bf16* vp = vt + (size_t)h * (DK * T_TOT);

  __shared__ __bf16 Ks[2][64 * 64];     // [kv][d-chunks swizzled]  8 KB x2
  __shared__ __bf16 Vs[2][64 * 64];     // [d][kv-chunks swizzled]  8 KB x2
  __shared__ __bf16 Ps[64 * 64];        // P [q][kv-chunks swizzled] 8 KB (single buf)
  __shared__ float  lred[4][64];        // per-wave partial row sums

  // Q B-frags (persistent, 32 VGPR): B[k=d=quad*8+e][n=q=qt*16+lc]
  bf16x8 qf[4][2];
#pragma unroll
  for (int qt = 0; qt < 4; qt++)
#pragma unroll
    for (int kk = 0; kk < 2; kk++)
      qf[qt][kk] = *(const bf16x8*)(qp + (size_t)(q0b + qt * 16 + lc) * DK + kk * 32 + quad * 8);

  f32x16 acc_o;                         // O^T tile [32d][32q] per wave (m74 layout)
#pragma unroll
  for (int e = 0; e < 16; e++) acc_o[e] = 0.f;
  float lp[4] = {0.f, 0.f, 0.f, 0.f};   // partial row-sums, q = qt*16+lc

  const int jstart = (q0b >= SLEN + SEQ) ? 2 : 0;   // 64-kv tiles
  const int jend   = qg;

  auto stage = [&](int j, int bufi) {
    const __bf16* kT = kp + (size_t)j * 64 * DK;
#pragma unroll
    for (int it = 0; it < 2; ++it) {
      int L = it * 256 + tid;
      int row = L >> 3, c = (L & 7) ^ ((L >> 3) & 7);
      async_copy16(kT + (size_t)row * DK + c * 8,
                   (char*)&Ks[bufi][0] + (size_t)(it * 256 + wave * 64) * 16);
    }
#pragma unroll
    for (int it = 0; it < 2; ++it) {
      int L = it * 256 + tid;
      int d = L >> 3, c = (L & 7) ^ ((L >> 3) & 7);
      async_copy16(vp + (size_t)d * T_TOT + j * 64 + c * 8,
                   (char*)&Vs[bufi][0] + (size_t)(it * 256 + wave * 64) * 16);
    }
  };

  stage(jstart, 0);
  int cur = 0;

  const int d0 = (wave >> 1) * 32;      // this wave's PV d-tile
  const int q0 = (wave & 1) * 32;       // this wave's PV q-tile

  for (int j = jstart; j <= jend; ++j) {
    __syncthreads();                    // drain staging of tile j; protect Ps
    if (j < jend) stage(j + 1, cur ^ 1);

    const bool diag = (j == jend);

    // ---- S^T slice: kv = wave*16 + quad*4 + r ; q = qt*16 + lc
    bf16x8 kA[2];
#pragma unroll
    for (int kk = 0; kk < 2; kk++) {
      int row = wave * 16 + lc;
      kA[kk] = *(const bf16x8*)(&Ks[cur][(row * 8 + ((kk * 4 + quad) ^ (lc & 7))) * 8]);
    }
    f32x4 s[4];
#pragma unroll
    for (int qt = 0; qt < 4; qt++) {
      s[qt] = (f32x4){0.f, 0.f, 0.f, 0.f};
#pragma unroll
      for (int kk = 0; kk < 2; kk++)
        s[qt] = __builtin_amdgcn_mfma_f32_16x16x32_bf16(kA[kk], qf[qt][kk], s[qt], 0, 0, 0);
    }

    // ---- fixed-shift softmax (exact: q,k l2-normed, scores bounded) + P write
#pragma unroll
    for (int qt = 0; qt < 4; qt++) {
      if (diag) {
#pragma unroll
        for (int r = 0; r < 4; r++)
          if ((wave * 16 + quad * 4 + r) > (qt * 16 + lc)) s[qt][r] = -__builtin_inff();
      }
      bf16x4 pb;
#pragma unroll
      for (int r = 0; r < 4; r++) {
        float pe = exp2f(s[qt][r]);
        lp[qt] += pe;
        pb[r] = (__bf16)pe;
      }
      int el = (qt * 16 + lc) * 64 + (((wave * 2 + (quad >> 1)) ^ (lc & 7)) * 8) + (quad & 1) * 4;
      *(bf16x4*)(&Ps[el]) = pb;
    }

    lds_barrier();                      // P visible to all waves; prefetch unharmed

    // ---- O^T[32d][32q] += V^T P^T  (32x32x16 MFMA, 4 k-steps over 64 kv)
#pragma unroll
    for (int ks = 0; ks < 4; ks++) {
      int ch = (ks * 2 + hi) ^ (l32 & 7);
      bf16x8 vA = *(const bf16x8*)(&Vs[cur][((d0 + l32) * 8 + ch) * 8]);
      bf16x8 pB = *(const bf16x8*)(&Ps[((q0 + l32) * 8 + ch) * 8]);
      acc_o = __builtin_amdgcn_mfma_f32_32x32x16_bf16(vA, pB, acc_o, 0, 0, 0);
    }
    cur ^= 1;
  }

  // ---- l reduction: over quads (shuffles), then across waves (LDS)
#pragma unroll
  for (int qt = 0; qt < 4; qt++) {
    lp[qt] += __shfl_xor(lp[qt], 16, 64);
    lp[qt] += __shfl_xor(lp[qt], 32, 64);
  }
  lred[wave][quad * 16 + lc] = lp[quad];
  __syncthreads();
  float lsum = lred[0][q0 + l32] + lred[1][q0 + l32] + lred[2][q0 + l32] + lred[3][q0 + l32];
  float invl = 1.0f / lsum;

  // ---- store: O[q][d] = acc/l ; C layout: q = q0+l32, d = d0 + 4*hi + 8*g + t
  const size_t rowbase = ((size_t)h * T_TOT + q0b + q0 + l32) * DK;
#pragma unroll
  for (int g = 0; g < 4; g++) {
    f32x4 o;
#pragma unroll
    for (int t = 0; t < 4; t++) o[t] = acc_o[g * 4 + t] * invl;
    *(f32x4*)(&out[rowbase + d0 + 4 * hi + 8 * g]) = o;
  }
}

extern "C" void kernel_launch(void* const* d_in, const int* in_sizes, int n_in,
                              void* d_out, int out_size, void* d_ws, size_t ws_size,
                              hipStream_t stream) {
  const float* x    = (const float*)d_in[0];
  const float* Wq   = (const float*)d_in[1];
  const float* Wk   = (const float*)d_in[2];
  const float* Wv   = (const float*)d_in[3];
  const float* Wqs  = (const float*)d_in[4];
  const float* Wks  = (const float*)d_in[5];
  const float* Wvs  = (const float*)d_in[6];
  const float* scal = (const float*)d_in[7];
  float* out = (float*)d_out;

  char* ws = (char*)d_ws;
  size_t off = 0;
  __bf16* xb  = (__bf16*)(ws + off); off += (size_t)T_TOT * DDIM * 2;
  __bf16* Wt  = (__bf16*)(ws + off); off += (size_t)6 * NH * DK * DDIM * 2;
  __bf16* qkv = (__bf16*)(ws + off); off += (size_t)2 * NH * T_TOT * DK * 2;
  __bf16* vt  = (__bf16*)(ws + off);

  convert_kernel<<<2112, 256, 0, stream>>>(x, Wq, Wk, Wv, Wqs, Wks, Wvs, xb, Wt);
  proj_kernel<<<dim3(8, 18, 3), 256, 0, stream>>>(xb, Wt, scal, qkv, vt);
  attn_kernel<<<dim3(576), 256, 0, stream>>>(qkv, vt, out);
}

// Round 12
// 148.510 us; speedup vs baseline: 1.4229x; 1.0485x over previous
//
#include <hip/hip_runtime.h>
#include <hip/hip_bf16.h>

#define T_TOT 2304
#define DDIM  1024
#define NH    16
#define DK    64
#define SLEN  128
#define SEQ   2048

typedef __bf16 bf16x8 __attribute__((ext_vector_type(8)));
typedef __bf16 bf16x4 __attribute__((ext_vector_type(4)));
typedef float  f32x4  __attribute__((ext_vector_type(4)));
typedef float  f32x16 __attribute__((ext_vector_type(16)));

__device__ __forceinline__ void async_copy16(const void* gsrc, void* ldst) {
  __builtin_amdgcn_global_load_lds(
      (const __attribute__((address_space(1))) void*)gsrc,
      (__attribute__((address_space(3))) void*)ldst, 16, 0, 0);
}

// LDS-only barrier: waits own LDS ops, joins waves, does NOT drain vmcnt.
__device__ __forceinline__ void lds_barrier() {
  __asm__ volatile("s_waitcnt lgkmcnt(0)\n\ts_barrier" ::: "memory");
}

// ---------------- convert: x -> bf16 (vectorized); W[h][d][n] -> Wt[m][h][n][d] via LDS transpose
__global__ __launch_bounds__(256) void convert_kernel(
    const float* __restrict__ x,
    const float* __restrict__ Wq, const float* __restrict__ Wk,
    const float* __restrict__ Wv, const float* __restrict__ Wqs,
    const float* __restrict__ Wks, const float* __restrict__ Wvs,
    __bf16* __restrict__ xb, __bf16* __restrict__ Wt) {
  const int b = blockIdx.x;
  const int tid = threadIdx.x;
  if (b < 576) {
    const float4* xin = (const float4*)x;
#pragma unroll
    for (int it = 0; it < 4; ++it) {
      int idx4 = b * 1024 + it * 256 + tid;
      float4 v = xin[idx4];
      bf16x4 o;
      o[0] = (__bf16)v.x; o[1] = (__bf16)v.y; o[2] = (__bf16)v.z; o[3] = (__bf16)v.w;
      *(bf16x4*)(xb + (size_t)idx4 * 4) = o;
    }
    return;
  }
  __shared__ float tile[64 * 65];
  const int wb = b - 576;
  const int m  = wb >> 8;
  const int rem = wb & 255;
  const int h  = rem >> 4;
  const int dt = rem & 15;
  const int d0 = dt * 64;
  const float* Wsrc = (m == 0 ? Wq : m == 1 ? Wk : m == 2 ? Wv
                      : m == 3 ? Wqs : m == 4 ? Wks : Wvs) + (size_t)h * (DDIM * DK);
#pragma unroll
  for (int rr = 0; rr < 4; ++rr) {
    int drow = rr * 16 + (tid >> 4);
    int nc   = (tid & 15) * 4;
    float4 v = *(const float4*)(Wsrc + (size_t)(d0 + drow) * DK + nc);
    tile[(nc + 0) * 65 + drow] = v.x;
    tile[(nc + 1) * 65 + drow] = v.y;
    tile[(nc + 2) * 65 + drow] = v.z;
    tile[(nc + 3) * 65 + drow] = v.w;
  }
  __syncthreads();
  {
    int n  = tid >> 2;
    int rg = (tid & 3) * 16;
    __bf16* dst = Wt + (((size_t)(m * NH + h)) * DK + n) * DDIM + d0 + rg;
    bf16x8 o0, o1;
#pragma unroll
    for (int e = 0; e < 8; e++) o0[e] = (__bf16)tile[n * 65 + rg + e];
#pragma unroll
    for (int e = 0; e < 8; e++) o1[e] = (__bf16)tile[n * 65 + rg + 8 + e];
    *(bf16x8*)dst = o0;
    *(bf16x8*)(dst + 8) = o1;
  }
}

// ---------------- proj v2: m97-shape GEMM 128x128 tile, N=1024 (all 16 heads fused)
// q is pre-scaled by scal[h]*log2(e) so attn softmax can use exp2 directly.
__global__ __launch_bounds__(256) void proj_kernel(
    const __bf16* __restrict__ xb, const __bf16* __restrict__ Wt,
    const float* __restrict__ scal,
    __bf16* __restrict__ qkv, __bf16* __restrict__ vt) {
  const int ntile = blockIdx.x;   // 0..7
  const int rt    = blockIdx.y;   // 0..17
  const int which = blockIdx.z;   // 0=q 1=k 2=v
  const int r0    = rt * 128;
  const int m     = (rt == 0 || rt == 17) ? which + 3 : which;

  __shared__ __bf16 Xs[128 * 64];
  __shared__ __bf16 Wsh[128 * 64];

  const int tid  = threadIdx.x;
  const int wave = tid >> 6, lane = tid & 63;
  const int quad = lane >> 4, lc = lane & 15;
  const int wr   = wave >> 1, wc = wave & 1;
  const int h    = ntile * 2 + wc;

  const __bf16* Wbase = Wt + ((size_t)m * NH) * (DK * DDIM) + (size_t)(ntile * 128) * DDIM;

  const f32x4 fz = {0.f, 0.f, 0.f, 0.f};
  f32x4 acc[4][4];
#pragma unroll
  for (int i = 0; i < 4; i++)
#pragma unroll
    for (int j = 0; j < 4; j++) acc[i][j] = fz;

  for (int k0 = 0; k0 < DDIM; k0 += 64) {
#pragma unroll
    for (int it = 0; it < 4; ++it) {
      int L = it * 256 + tid;
      int row = L >> 3, c = (L & 7) ^ ((L >> 3) & 7);
      async_copy16(xb + (size_t)(r0 + row) * DDIM + k0 + c * 8,
                   (char*)Xs + (size_t)(it * 256 + wave * 64) * 16);
    }
#pragma unroll
    for (int it = 0; it < 4; ++it) {
      int L = it * 256 + tid;
      int row = L >> 3, c = (L & 7) ^ ((L >> 3) & 7);
      async_copy16(Wbase + (size_t)row * DDIM + k0 + c * 8,
                   (char*)Wsh + (size_t)(it * 256 + wave * 64) * 16);
    }
    __syncthreads();
#pragma unroll
    for (int kk = 0; kk < 2; kk++) {
      bf16x8 afr[4], bfr[4];
#pragma unroll
      for (int i = 0; i < 4; i++) {
        int row = wr * 64 + i * 16 + lc;
        int ch  = (kk * 4 + quad) ^ (row & 7);
        afr[i] = *(const bf16x8*)(Xs + (row * 8 + ch) * 8);
      }
#pragma unroll
      for (int j = 0; j < 4; j++) {
        int row = wc * 64 + j * 16 + lc;
        int ch  = (kk * 4 + quad) ^ (row & 7);
        bfr[j] = *(const bf16x8*)(Wsh + (row * 8 + ch) * 8);
      }
#pragma unroll
      for (int i = 0; i < 4; i++)
#pragma unroll
        for (int j = 0; j < 4; j++)
          acc[i][j] = __builtin_amdgcn_mfma_f32_16x16x32_bf16(afr[i], bfr[j], acc[i][j], 0, 0, 0);
    }
    __syncthreads();
  }

  const float qscale = (which == 0) ? scal[h] * 1.44269504088896f : 1.0f;
  float inv4[4][4];
#pragma unroll
  for (int i = 0; i < 4; i++) {
#pragma unroll
    for (int r = 0; r < 4; r++) {
      float s = 0.f;
#pragma unroll
      for (int j = 0; j < 4; j++) { float v = acc[i][j][r]; s += v * v; }
#pragma unroll
      for (int off = 1; off < 16; off <<= 1) s += __shfl_xor(s, off, 64);
      inv4[i][r] = qscale / fmaxf(sqrtf(s), 1e-12f);
    }
  }
  if (which == 2) {
    __bf16* vtp = vt + (size_t)h * (DK * T_TOT);
#pragma unroll
    for (int i = 0; i < 4; i++) {
      int rowbase = r0 + wr * 64 + i * 16 + quad * 4;
#pragma unroll
      for (int j = 0; j < 4; j++) {
        bf16x4 o;
#pragma unroll
        for (int r = 0; r < 4; r++) o[r] = (__bf16)(acc[i][j][r] * inv4[i][r]);
        *(bf16x4*)(vtp + (size_t)(j * 16 + lc) * T_TOT + rowbase) = o;
      }
    }
  } else {
    __bf16* outp = qkv + ((size_t)(which * NH + h)) * ((size_t)T_TOT * DK);
#pragma unroll
    for (int i = 0; i < 4; i++)
#pragma unroll
      for (int r = 0; r < 4; r++) {
        int row = r0 + wr * 64 + i * 16 + quad * 4 + r;
#pragma unroll
        for (int j = 0; j < 4; j++)
          outp[(size_t)row * DK + j * 16 + lc] = (__bf16)(acc[i][j][r] * inv4[i][r]);
      }
  }
}

// ---------------- flash attention v11: split-K (2 blocks per (h,64q)), kv-sliced S,
// 32x32x16 PV, fixed-shift softmax. Partials (unnormalized O + l) to ws;
// combine is a pure sum (no max tracking needed -> no log-sum-exp).
__global__ __launch_bounds__(256, 3) void attn_kernel(
    const __bf16* __restrict__ qkv, const __bf16* __restrict__ vt,
    float* __restrict__ Opart, float* __restrict__ Lpart) {
  const int b    = blockIdx.x;          // 0..1151
  const int h    = b & 15;
  const int rest = b >> 4;              // 0..71
  const int qg   = 35 - (rest >> 1);    // big work first
  const int si   = rest & 1;            // kv split index
  const int q0b  = qg * 64;
  const int tid  = threadIdx.x;
  const int wave = tid >> 6, lane = tid & 63;
  const int quad = lane >> 4, lc = lane & 15;
  const int l32  = lane & 31, hi = lane >> 5;

  const __bf16* qp = qkv + ((size_t)h) * ((size_t)T_TOT * DK);
  const __bf16* kp = qkv + ((size_t)(NH + h)) * ((size_t)T_TOT * DK);
  const __bf16* vp = vt + (size_t)h * (DK * T_TOT);

  __shared__ __bf16 Ks[2][64 * 64];     // 8 KB x2
  __shared__ __bf16 Vs[2][64 * 64];     // 8 KB x2
  __shared__ __bf16 Ps[64 * 64];        // 8 KB
  __shared__ float  lred[4][64];

  // Q B-frags (persistent): B[k=d][n=q=qt*16+lc]
  bf16x8 qf[4][2];
#pragma unroll
  for (int qt = 0; qt < 4; qt++)
#pragma unroll
    for (int kk = 0; kk < 2; kk++)
      qf[qt][kk] = *(const bf16x8*)(qp + (size_t)(q0b + qt * 16 + lc) * DK + kk * 32 + quad * 8);

  f32x16 acc_o;                         // O^T tile [32d][32q] per wave
#pragma unroll
  for (int e = 0; e < 16; e++) acc_o[e] = 0.f;
  float lp[4] = {0.f, 0.f, 0.f, 0.f};

  // kv range for this split
  const int jsAll = (q0b >= SLEN + SEQ) ? 2 : 0;
  const int n     = qg - jsAll + 1;
  const int half  = (n + 1) >> 1;
  const int j0    = jsAll + (si ? half : 0);
  const int j1    = si ? qg : (jsAll + half - 1);

  auto stage = [&](int j, int bufi) {
    const __bf16* kT = kp + (size_t)j * 64 * DK;
#pragma unroll
    for (int it = 0; it < 2; ++it) {
      int L = it * 256 + tid;
      int row = L >> 3, c = (L & 7) ^ ((L >> 3) & 7);
      async_copy16(kT + (size_t)row * DK + c * 8,
                   (char*)&Ks[bufi][0] + (size_t)(it * 256 + wave * 64) * 16);
    }
#pragma unroll
    for (int it = 0; it < 2; ++it) {
      int L = it * 256 + tid;
      int d = L >> 3, c = (L & 7) ^ ((L >> 3) & 7);
      async_copy16(vp + (size_t)d * T_TOT + j * 64 + c * 8,
                   (char*)&Vs[bufi][0] + (size_t)(it * 256 + wave * 64) * 16);
    }
  };

  int cur = 0;
  if (j0 <= j1) stage(j0, 0);

  const int d0 = (wave >> 1) * 32;      // PV d-tile
  const int q0 = (wave & 1) * 32;       // PV q-tile

  for (int j = j0; j <= j1; ++j) {
    __syncthreads();                    // drain staging of tile j; protect Ps
    if (j < j1) stage(j + 1, cur ^ 1);

    const bool diag = (j == qg);

    // S^T slice: kv = wave*16 + quad*4 + r ; q = qt*16 + lc
    bf16x8 kA[2];
#pragma unroll
    for (int kk = 0; kk < 2; kk++) {
      int row = wave * 16 + lc;
      kA[kk] = *(const bf16x8*)(&Ks[cur][(row * 8 + ((kk * 4 + quad) ^ (lc & 7))) * 8]);
    }
    f32x4 s[4];
#pragma unroll
    for (int qt = 0; qt < 4; qt++) {
      s[qt] = (f32x4){0.f, 0.f, 0.f, 0.f};
#pragma unroll
      for (int kk = 0; kk < 2; kk++)
        s[qt] = __builtin_amdgcn_mfma_f32_16x16x32_bf16(kA[kk], qf[qt][kk], s[qt], 0, 0, 0);
    }

    // fixed-shift softmax + P write
#pragma unroll
    for (int qt = 0; qt < 4; qt++) {
      if (diag) {
#pragma unroll
        for (int r = 0; r < 4; r++)
          if ((wave * 16 + quad * 4 + r) > (qt * 16 + lc)) s[qt][r] = -__builtin_inff();
      }
      bf16x4 pb;
#pragma unroll
      for (int r = 0; r < 4; r++) {
        float pe = exp2f(s[qt][r]);
        lp[qt] += pe;
        pb[r] = (__bf16)pe;
      }
      int el = (qt * 16 + lc) * 64 + (((wave * 2 + (quad >> 1)) ^ (lc & 7)) * 8) + (quad & 1) * 4;
      *(bf16x4*)(&Ps[el]) = pb;
    }

    lds_barrier();                      // P visible; prefetch stays in flight

    // O^T[32d][32q] += V^T P^T  (32x32x16 MFMA, 4 k-steps)
#pragma unroll
    for (int ks = 0; ks < 4; ks++) {
      int ch = (ks * 2 + hi) ^ (l32 & 7);
      bf16x8 vA = *(const bf16x8*)(&Vs[cur][((d0 + l32) * 8 + ch) * 8]);
      bf16x8 pB = *(const bf16x8*)(&Ps[((q0 + l32) * 8 + ch) * 8]);
      acc_o = __builtin_amdgcn_mfma_f32_32x32x16_bf16(vA, pB, acc_o, 0, 0, 0);
    }
    cur ^= 1;
  }

  // l reduction: quads via shuffle, waves via LDS; store per-block partials
#pragma unroll
  for (int qt = 0; qt < 4; qt++) {
    lp[qt] += __shfl_xor(lp[qt], 16, 64);
    lp[qt] += __shfl_xor(lp[qt], 32, 64);
  }
  lred[wave][quad * 16 + lc] = lp[quad];
  __syncthreads();
  if (wave == 0)
    Lpart[(size_t)b * 64 + lane] = lred[0][lane] + lred[1][lane] + lred[2][lane] + lred[3][lane];

  // store unnormalized O partial: [q][d] layout
  float* Ob = Opart + (size_t)b * 4096;
  const size_t rowbase = (size_t)(q0 + l32) * DK;
#pragma unroll
  for (int g = 0; g < 4; g++) {
    f32x4 o;
#pragma unroll
    for (int t = 0; t < 4; t++) o[t] = acc_o[g * 4 + t];
    *(f32x4*)(&Ob[rowbase + d0 + 4 * hi + 8 * g]) = o;
  }
}

// ---------------- combine: out = (O0 + O1) / (l0 + l1)
__global__ __launch_bounds__(256) void combine_kernel(
    const float* __restrict__ Opart, const float* __restrict__ Lpart,
    float* __restrict__ out) {
  const int b  = blockIdx.x;            // 0..575
  const int h  = b & 15;
  const int qg = b >> 4;
  const int b0 = (((35 - qg) * 2) << 4) | h;
  const int b1 = b0 + 16;
  const int tid = threadIdx.x;

  __shared__ float invl[64];
  if (tid < 64)
    invl[tid] = 1.0f / (Lpart[(size_t)b0 * 64 + tid] + Lpart[(size_t)b1 * 64 + tid]);
  __syncthreads();

  const float* O0 = Opart + (size_t)b0 * 4096;
  const float* O1 = Opart + (size_t)b1 * 4096;
  float* op = out + ((size_t)h * T_TOT + qg * 64) * DK;
#pragma unroll
  for (int it = 0; it < 4; ++it) {
    int i4 = it * 256 + tid;            // vec4 index, 0..1023
    f32x4 a = *(const f32x4*)(&O0[i4 * 4]);
    f32x4 c = *(const f32x4*)(&O1[i4 * 4]);
    float iv = invl[i4 >> 4];
    f32x4 o;
#pragma unroll
    for (int r = 0; r < 4; r++) o[r] = (a[r] + c[r]) * iv;
    *(f32x4*)(&op[i4 * 4]) = o;
  }
}

extern "C" void kernel_launch(void* const* d_in, const int* in_sizes, int n_in,
                              void* d_out, int out_size, void* d_ws, size_t ws_size,
                              hipStream_t stream) {
  const float* x    = (const float*)d_in[0];
  const float* Wq   = (const float*)d_in[1];
  const float* Wk   = (const float*)d_in[2];
  const float* Wv   = (const float*)d_in[3];
  const float* Wqs  = (const float*)d_in[4];
  const float* Wks  = (const float*)d_in[5];
  const float* Wvs  = (const float*)d_in[6];
  const float* scal = (const float*)d_in[7];
  float* out = (float*)d_out;

  char* ws = (char*)d_ws;
  size_t off = 0;
  __bf16* xb    = (__bf16*)(ws + off); off += (size_t)T_TOT * DDIM * 2;
  __bf16* Wt    = (__bf16*)(ws + off); off += (size_t)6 * NH * DK * DDIM * 2;
  __bf16* qkv   = (__bf16*)(ws + off); off += (size_t)2 * NH * T_TOT * DK * 2;
  __bf16* vt    = (__bf16*)(ws + off); off += (size_t)NH * DK * T_TOT * 2;
  float*  Opart = (float*)(ws + off);  off += (size_t)1152 * 4096 * 4;
  float*  Lpart = (float*)(ws + off);

  convert_kernel<<<2112, 256, 0, stream>>>(x, Wq, Wk, Wv, Wqs, Wks, Wvs, xb, Wt);
  proj_kernel<<<dim3(8, 18, 3), 256, 0, stream>>>(xb, Wt, scal, qkv, vt);
  attn_kernel<<<dim3(1152), 256, 0, stream>>>(qkv, vt, Opart, Lpart);
  combine_kernel<<<dim3(576), 256, 0, stream>>>(Opart, Lpart, out);
}